// Round 8
// baseline (1589.795 us; speedup 1.0000x reference)
//
#include <hip/hip_runtime.h>

// VQ-VAE EMA vector quantizer, MI355X.
// R8: argmin restructured for read/MFMA overlap — cross-iteration fragment
// ping-pong (read frags(g+1) while MFMA(g) runs; consumers 1 iter away so no
// lgkm stall), BC=256 (acc 64 AGPR -> room for 2 frag sets), 4 LDS buffers
// (formal WAR safety), cnorm in LDS (no epilogue vmem drain), counted vmcnt(3).
// exact_kernel: wave-per-code coalesced. R7 scatter path unchanged.

constexpr int N = 32768;   // B*L
constexpr int D = 512;
constexpr int K = 8192;

constexpr float DECAYF  = 0.99f;
constexpr float OMDECAY = (float)(1.0 - 0.99);
constexpr float EPSF    = 1e-6f;
constexpr float KEPSF   = (float)(8192 * 1e-6);
constexpr float TAU     = 0.02f;   // gap threshold for exact re-check

typedef unsigned int   u32;
typedef unsigned short u16;
typedef float  f32x4 __attribute__((ext_vector_type(4)));
typedef u32    u32x4 __attribute__((ext_vector_type(4)));
typedef __bf16 bf16x8 __attribute__((ext_vector_type(8)));

#define AS1 __attribute__((address_space(1)))
#define AS3 __attribute__((address_space(3)))

// ---- workspace layout (32-bit word offsets) ----
constexpr size_t OFF_CNORM   = 0;                        // K floats
constexpr size_t OFF_IDX     = OFF_CNORM + K;            // N int
constexpr size_t OFF_CNTI    = OFF_IDX + N;              // K int
constexpr size_t OFF_NEXT    = OFF_CNTI + K;             // K int
constexpr size_t OFF_OFFS    = OFF_NEXT + K;             // K+1 int
constexpr size_t OFF_LIST    = OFF_OFFS + K + 2;         // N int (pad->even)
constexpr size_t OFF_SUMS    = OFF_LIST + N;             // 2 words = 1 double (n_sum), EVEN
constexpr size_t OFF_FLAGC   = OFF_SUMS + 2;             // 1 int
constexpr size_t OFF_FLAGL   = OFF_FLAGC + 1;            // N int
constexpr size_t OFF_LOSSP   = ((OFF_FLAGL + N + 1) & ~(size_t)1); // N/2 doubles, EVEN
static_assert((OFF_SUMS & 1) == 0, "n_sum must be 8-byte aligned");
static_assert((OFF_LOSSP & 1) == 0, "loss partials must be 8-byte aligned");

// ---- output layout (float offsets), reference return order ----
constexpr size_t OUT_ZQ   = 0;                          // N*D (scratch: X2 until zq_loss)
constexpr size_t OUT_IDX  = OUT_ZQ + (size_t)N * D;     // N
constexpr size_t OUT_LOSS = OUT_IDX + N;                // 1
constexpr size_t OUT_NCB  = OUT_LOSS + 1;               // K*D (scratch: CB2 until finalize)
constexpr size_t OUT_NCS  = OUT_NCB + (size_t)K * D;    // K
constexpr size_t OUT_EMA  = OUT_NCS + K;                // K*D

// ---------------------------------------------------------------------------
__device__ inline u16 f32_to_bf16_rne(float f)
{
    u32 u = __builtin_bit_cast(u32, f);
    u = (u + 0x7FFFu + ((u >> 16) & 1u)) >> 16;
    return (u16)u;
}

// split f32 -> (hi,lo) bf16 pairs in MFMA FRAGMENT ORDER, coalesced writes.
// Layout [rows/16][32 k-slices][64 lanes][8]: elem ((R*32+S)*64+l)*8+j2 holds
// M[R*16+(l&15)][k=S*32+(l>>4)*8+j2], k=2d->hi(d), k=2d+1->lo(d).
__global__ __launch_bounds__(256) void split_frag_kernel(const float* __restrict__ src,
                                                         u32x4* __restrict__ dst)
{
    const int R = blockIdx.x;
    const int w = threadIdx.x >> 6;
    const int l = threadIdx.x & 63;
    const int row = R * 16 + (l & 15);
    const int cq  = l >> 4;
#pragma unroll
    for (int i = 0; i < 8; ++i) {
        const int S = w + 4 * i;
        const float4 v = ((const float4*)src)[(size_t)row * 128 + S * 4 + cq];
        u32x4 o;
        const float a[4] = {v.x, v.y, v.z, v.w};
#pragma unroll
        for (int j = 0; j < 4; ++j) {
            const u16 hi = f32_to_bf16_rne(a[j]);
            const float hif = __builtin_bit_cast(float, (u32)hi << 16);
            const u16 lo = f32_to_bf16_rne(a[j] - hif);
            ((u32*)&o)[j] = (u32)hi | ((u32)lo << 16);
        }
        dst[((size_t)R * 32 + S) * 64 + l] = o;
    }
}

// ---------------------------------------------------------------------------
__global__ __launch_bounds__(256) void row_norm_kernel(const float* __restrict__ a,
                                                       float* __restrict__ out)
{
    const int row  = blockIdx.x * 4 + (threadIdx.x >> 6);
    const int lane = threadIdx.x & 63;
    const float4* r = (const float4*)(a + (size_t)row * D);
    const float4 v0 = r[lane];
    const float4 v1 = r[lane + 64];
    float s = v0.x * v0.x + v0.y * v0.y + v0.z * v0.z + v0.w * v0.w
            + v1.x * v1.x + v1.y * v1.y + v1.z * v1.z + v1.w * v1.w;
#pragma unroll
    for (int m = 32; m >= 1; m >>= 1) s += __shfl_xor(s, m, 64);
    if (lane == 0) out[row] = s;
}

// ---------------------------------------------------------------------------
// MFMA argmin. 512 thr (8 waves), 128 points/block, 256-code chunks (32/wave).
// Cross-iteration ping-pong: iter g reads frags(g+1) into the idle set while
// MFMA(g) runs on the other; 4 buffers; counted vmcnt(3); cnorm in LDS.
constexpr int BP = 128, BC = 256, KI = 32;
constexpr int NSTEP = 1024 / KI, NCHUNK = K / BC, TOTAL = NCHUNK * NSTEP; // 32,32,1024
constexpr int CELEMS = BC * KI;            // 8192 u16 (16KB)
constexpr int XELEMS = BP * KI;            // 4096 u16 (8KB)
constexpr int BUFE = CELEMS + XELEMS;      // 12288 u16 (24KB)

__global__ __launch_bounds__(512, 2) void argmin_mfma_kernel(
    const u16* __restrict__ CB2, const u16* __restrict__ X2,
    const float* __restrict__ cnorm,
    int* __restrict__ idx_i, float* __restrict__ idx_f,
    int* __restrict__ flag_cnt, int* __restrict__ flag_list)
{
    __shared__ __align__(16) u16 lds[4 * BUFE + 16384];   // 96KB bufs + 32KB cnorm

    const int tid  = threadIdx.x;
    const int w    = tid >> 6;
    const int lane = tid & 63;
    const int lhi  = lane >> 4;
    const int n0   = blockIdx.x * BP;
    float* cn_lds  = (float*)&lds[4 * BUFE];

    auto stage = [&](int g) {   // 3 global_load_lds per thread
        u16* bufp = &lds[(g & 3) * BUFE];
        const int c = g >> 5, s = g & 31;
#pragma unroll
        for (int j = 0; j < 2; ++j) {
            const int slot = j * 512 + tid;
            const u16* gsrc = CB2 + (((size_t)(c * 16 + (slot >> 6)) * 32 + s) * 512
                                     + (slot & 63) * 8);
            __builtin_amdgcn_global_load_lds((const AS1 u32*)gsrc,
                                             (AS3 u32*)(bufp + slot * 8), 16, 0, 0);
        }
        const u16* gx = X2 + (((size_t)(n0 / 16 + (tid >> 6)) * 32 + s) * 512
                              + (tid & 63) * 8);
        __builtin_amdgcn_global_load_lds((const AS1 u32*)gx,
                                         (AS3 u32*)(bufp + CELEMS + tid * 8), 16, 0, 0);
    };

    float b1[8], b2[8]; int i1[8];
#pragma unroll
    for (int p = 0; p < 8; ++p) { b1[p] = INFINITY; b2[p] = INFINITY; i1[p] = 0; }

    f32x4 acc[2][8];
    const f32x4 zero = {0.f, 0.f, 0.f, 0.f};
#pragma unroll
    for (int i = 0; i < 2; ++i)
#pragma unroll
        for (int p = 0; p < 8; ++p) acc[i][p] = zero;

    u32x4 afA[2], bfA[8], afB[2], bfB[8];

    auto loadf = [&](u32x4 (&af)[2], u32x4 (&bfr)[8], const u16* buf) {
#pragma unroll
        for (int p = 0; p < 8; ++p)
            bfr[p] = *(const u32x4*)(buf + CELEMS + p * 512 + lane * 8);
#pragma unroll
        for (int i = 0; i < 2; ++i)
            af[i] = *(const u32x4*)(buf + (w * 2 + i) * 512 + lane * 8);
    };

    auto mfma_half = [&](u32x4 (&af)[2], u32x4 (&bfr)[8]) {
#pragma unroll
        for (int i = 0; i < 2; ++i) {
            u32x4 as;
            as.x = (af[i].x >> 16) | (af[i].x << 16);
            as.y = (af[i].y >> 16) | (af[i].y << 16);
            as.z = (af[i].z >> 16) | (af[i].z << 16);
            as.w = (af[i].w >> 16) | (af[i].w << 16);
#pragma unroll
            for (int p = 0; p < 8; ++p) {
                acc[i][p] = __builtin_amdgcn_mfma_f32_16x16x32_bf16(
                    __builtin_bit_cast(bf16x8, af[i]), __builtin_bit_cast(bf16x8, bfr[p]),
                    acc[i][p], 0, 0, 0);
                acc[i][p] = __builtin_amdgcn_mfma_f32_16x16x32_bf16(
                    __builtin_bit_cast(bf16x8, as), __builtin_bit_cast(bf16x8, bfr[p]),
                    acc[i][p], 0, 0, 0);
            }
        }
    };

    auto epilogue = [&](int chunk) {
#pragma unroll
        for (int i = 0; i < 2; ++i) {
            const int code0 = chunk * BC + (w * 2 + i) * 16 + lhi * 4;
            const float4 cn4 = *(const float4*)(cn_lds + code0);
            const float cn[4] = {cn4.x, cn4.y, cn4.z, cn4.w};
#pragma unroll
            for (int p = 0; p < 8; ++p) {
                const f32x4 A = acc[i][p];
                const float dv[4] = {cn[0] - 2.f * A.x, cn[1] - 2.f * A.y,
                                     cn[2] - 2.f * A.z, cn[3] - 2.f * A.w};
#pragma unroll
                for (int r = 0; r < 4; ++r) {
                    if (dv[r] < b1[p]) { b2[p] = b1[p]; b1[p] = dv[r]; i1[p] = code0 + r; }
                    else if (dv[r] < b2[p]) { b2[p] = dv[r]; }
                }
                acc[i][p] = zero;
            }
        }
    };

    // one pipeline iteration: compute step g on (afC,bfC); read step g+1 into
    // (afN,bfN) -- consumers one iter away, latency hides under MFMA cluster.
    auto iter = [&](u32x4 (&afC)[2], u32x4 (&bfC)[8],
                    u32x4 (&afN)[2], u32x4 (&bfN)[8], int g) {
        if (g + 2 < TOTAL) asm volatile("s_waitcnt vmcnt(3)" ::: "memory");
        else               asm volatile("s_waitcnt vmcnt(0)" ::: "memory");
        __builtin_amdgcn_s_barrier();
        __builtin_amdgcn_sched_barrier(0);
        if (g + 1 < TOTAL) loadf(afN, bfN, &lds[((g + 1) & 3) * BUFE]);
        if (g + 3 < TOTAL) stage(g + 3);
        __builtin_amdgcn_s_setprio(1);
        mfma_half(afC, bfC);
        __builtin_amdgcn_s_setprio(0);
        if ((g & (NSTEP - 1)) == NSTEP - 1) epilogue(g >> 5);
    };

    // prologue: cnorm -> LDS (4 loads) + stage 0,1; wait cnorm+stage0; read frags(0)
#pragma unroll
    for (int i2 = 0; i2 < 4; ++i2) {
        const int slot = i2 * 512 + tid;
        __builtin_amdgcn_global_load_lds((const AS1 u32*)(cnorm + slot * 4),
                                         (AS3 u32*)(cn_lds + slot * 4), 16, 0, 0);
    }
    stage(0);
    stage(1);
    asm volatile("s_waitcnt vmcnt(3)" ::: "memory");
    __builtin_amdgcn_s_barrier();
    __builtin_amdgcn_sched_barrier(0);
    loadf(afA, bfA, &lds[0]);
    stage(2);

    for (int g = 0; g < TOTAL; g += 2) {
        iter(afA, bfA, afB, bfB, g);
        iter(afB, bfB, afA, bfA, g + 1);
    }

    // cross-lane merge (lanes {p, p+16, p+32, p+48} hold same point's candidates)
#pragma unroll
    for (int p = 0; p < 8; ++p) {
#pragma unroll
        for (int m = 16; m <= 32; m <<= 1) {
            const float ob1 = __shfl_xor(b1[p], m, 64);
            const float ob2 = __shfl_xor(b2[p], m, 64);
            const int   oi1 = __shfl_xor(i1[p], m, 64);
            const float nb2 = fminf(fminf(b2[p], ob2), fmaxf(b1[p], ob1));
            if (ob1 < b1[p] || (ob1 == b1[p] && oi1 < i1[p])) { b1[p] = ob1; i1[p] = oi1; }
            b2[p] = nb2;
        }
    }

    __syncthreads();   // full drain before LDS reuse

    float* mb1 = (float*)&lds[0];
    float* mb2 = mb1 + 8 * BP;
    int*   mi  = (int*)(mb2 + 8 * BP);
    if (lane < 16) {
#pragma unroll
        for (int p = 0; p < 8; ++p) {
            const int pt = p * 16 + lane;
            mb1[w * BP + pt] = b1[p];
            mb2[w * BP + pt] = b2[p];
            mi [w * BP + pt] = i1[p];
        }
    }
    __syncthreads();
    if (tid < BP) {
        float fb1 = INFINITY, fb2 = INFINITY; int fi = 0;
        for (int ww = 0; ww < 8; ++ww) {
            const float a1 = mb1[ww * BP + tid], a2 = mb2[ww * BP + tid];
            const int   ai = mi[ww * BP + tid];
            const float nb2 = fminf(fminf(fb2, a2), fmaxf(fb1, a1));
            if (a1 < fb1 || (a1 == fb1 && ai < fi)) { fb1 = a1; fi = ai; }
            fb2 = nb2;
        }
        const int n = n0 + tid;
        idx_i[n] = fi;
        idx_f[n] = (float)fi;
        if (fb2 - fb1 < TAU) {
            const int pos = atomicAdd(flag_cnt, 1);
            if ((unsigned)pos < (unsigned)N) flag_list[pos] = n;
        }
    }
}

// ---------------------------------------------------------------------------
// exact f32 re-scan for flagged points — wave-per-code, coalesced row reads.
// Wave wv owns codes [wv*2048,(wv+1)*2048) ascending; cross-wave tie -> lower wave.
__global__ __launch_bounds__(256) void exact_kernel(
    const float* __restrict__ x, const float* __restrict__ cb,
    const float* __restrict__ cnorm, const int* __restrict__ flag_cnt,
    const int* __restrict__ flag_list, int* __restrict__ idx_i, float* __restrict__ idx_f)
{
    __shared__ float xs[D];
    __shared__ float wbv[4];
    __shared__ int   wbi[4];
    const int cnt  = min(*flag_cnt, N);
    const int wv   = threadIdx.x >> 6;
    const int lane = threadIdx.x & 63;
    for (int i = blockIdx.x; i < cnt; i += gridDim.x) {
        const int n = flag_list[i] & (N - 1);
        __syncthreads();
        if (threadIdx.x < 128)
            ((float4*)xs)[threadIdx.x] = ((const float4*)(x + (size_t)n * D))[threadIdx.x];
        __syncthreads();
        const float4 xa = ((const float4*)xs)[lane * 2];
        const float4 xb = ((const float4*)xs)[lane * 2 + 1];
        float best = INFINITY; int besti = K;
        for (int k = wv * (K / 4); k < (wv + 1) * (K / 4); ++k) {
            const float4* c4 = (const float4*)(cb + (size_t)k * D) + lane * 2;
            const float4 ca = c4[0], cb4 = c4[1];
            float s = xa.x * ca.x + xa.y * ca.y + xa.z * ca.z + xa.w * ca.w
                    + xb.x * cb4.x + xb.y * cb4.y + xb.z * cb4.z + xb.w * cb4.w;
#pragma unroll
            for (int m = 32; m >= 1; m >>= 1) s += __shfl_xor(s, m, 64);
            const float dist = cnorm[k] - 2.0f * s;
            if (dist < best) { best = dist; besti = k; }
        }
        if (lane == 0) { wbv[wv] = best; wbi[wv] = besti; }
        __syncthreads();
        if (threadIdx.x == 0) {
            float fb = wbv[0]; int fi = wbi[0];
            for (int j = 1; j < 4; ++j)
                if (wbv[j] < fb) { fb = wbv[j]; fi = wbi[j]; }
            idx_i[n] = fi;
            idx_f[n] = (float)fi;
        }
        __syncthreads();
    }
}

// ---------------------------------------------------------------------------
// zq gather + loss partial (per-block) + integer counts. 2 points/block.
__global__ __launch_bounds__(256) void zq_loss_kernel(
    const float* __restrict__ x, const float* __restrict__ cb,
    const int* __restrict__ idx_i, float* __restrict__ zq,
    int* __restrict__ cnti, double* __restrict__ loss_part)
{
    const int sub = threadIdx.x >> 7;
    const int t   = threadIdx.x & 127;
    const int n   = blockIdx.x * 2 + sub;
    const int k   = idx_i[n] & (K - 1);
    const size_t xoff = (size_t)n * 128 + t;
    const size_t coff = (size_t)k * 128 + t;

    const float4 xv = ((const float4*)x)[xoff];
    const float4 qv = ((const float4*)cb)[coff];
    ((float4*)zq)[xoff] = qv;

    const float d0 = xv.x - qv.x, d1 = xv.y - qv.y;
    const float d2 = xv.z - qv.z, d3 = xv.w - qv.w;
    float sq = d0 * d0 + d1 * d1 + d2 * d2 + d3 * d3;

    if (t == 0) atomicAdd(&cnti[k], 1);

#pragma unroll
    for (int m = 32; m >= 1; m >>= 1) sq += __shfl_xor(sq, m, 64);
    __shared__ float partial[4];
    if ((threadIdx.x & 63) == 0) partial[threadIdx.x >> 6] = sq;
    __syncthreads();
    if (threadIdx.x == 0)
        loss_part[blockIdx.x] = (double)(partial[0] + partial[1] + partial[2] + partial[3]);
}

// ---------------------------------------------------------------------------
__global__ __launch_bounds__(256) void scan_kernel(
    const int* __restrict__ cnti, const float* __restrict__ csz,
    int* __restrict__ offs, int* __restrict__ nxt,
    float* __restrict__ ncs, double* __restrict__ n_sum)
{
    __shared__ int    tsum[256];
    __shared__ double dsum[256];
    const int t = threadIdx.x;
    const int base = t * 32;
    int s = 0;
    double dn = 0.0;
#pragma unroll
    for (int i = 0; i < 32; ++i) {
        const int c = cnti[base + i];
        s += c;
        const float v = DECAYF * csz[base + i] + OMDECAY * (float)c;
        ncs[base + i] = v;
        dn += (double)v;
    }
    tsum[t] = s; dsum[t] = dn;
    __syncthreads();
    int run = 0;
    for (int j = 0; j < t; ++j) run += tsum[j];
#pragma unroll
    for (int i = 0; i < 32; ++i) {
        offs[base + i] = run;
        nxt[base + i] = run;
        run += cnti[base + i];
    }
    if (t == 255) offs[K] = run;
    if (t == 0) {
        double tot = 0.0;
        for (int j = 0; j < 256; ++j) tot += dsum[j];
        n_sum[0] = tot;
    }
}

// ---------------------------------------------------------------------------
__global__ __launch_bounds__(256) void fill_kernel(
    const int* __restrict__ idx_i, int* __restrict__ nxt, int* __restrict__ list)
{
    const int p = blockIdx.x * 256 + threadIdx.x;
    const int k = idx_i[p] & (K - 1);
    const int pos = atomicAdd(&nxt[k], 1);
    if ((unsigned)pos < (unsigned)N) list[pos] = p;
}

// ---------------------------------------------------------------------------
__global__ __launch_bounds__(128) void gather_finalize_kernel(
    const float* __restrict__ x, const int* __restrict__ offs,
    const int* __restrict__ list, const float* __restrict__ ema_w,
    const float* __restrict__ ncs, const double* __restrict__ n_sum,
    float* __restrict__ new_ema, float* __restrict__ new_cb)
{
    const int k = blockIdx.x;
    const int t = threadIdx.x;
    const int beg = min(offs[k], N), end = min(offs[k + 1], N);
    float4 acc = {0.f, 0.f, 0.f, 0.f};
    for (int i = beg; i < end; ++i) {
        const int p = list[i] & (N - 1);
        const float4 v = ((const float4*)x)[(size_t)p * 128 + t];
        acc.x += v.x; acc.y += v.y; acc.z += v.z; acc.w += v.w;
    }
    const float n = (float)n_sum[0];
    const float csm = (ncs[k] + EPSF) / (n + KEPSF) * n;
    const size_t o = (size_t)k * 128 + t;
    const float4 e = ((const float4*)ema_w)[o];
    float4 ne;
    ne.x = DECAYF * e.x + OMDECAY * acc.x;
    ne.y = DECAYF * e.y + OMDECAY * acc.y;
    ne.z = DECAYF * e.z + OMDECAY * acc.z;
    ne.w = DECAYF * e.w + OMDECAY * acc.w;
    ((float4*)new_ema)[o] = ne;
    float4 nc;
    nc.x = ne.x / csm; nc.y = ne.y / csm; nc.z = ne.z / csm; nc.w = ne.w / csm;
    ((float4*)new_cb)[o] = nc;
}

// ---------------------------------------------------------------------------
__global__ __launch_bounds__(256) void loss_reduce_kernel(
    const double* __restrict__ loss_part, float* __restrict__ out_loss)
{
    __shared__ double red[256];
    const int t = threadIdx.x;
    double s = 0.0;
    for (int i = t; i < N / 2; i += 256) s += loss_part[i];
    red[t] = s;
    __syncthreads();
    for (int off = 128; off > 0; off >>= 1) {
        if (t < off) red[t] += red[t + off];
        __syncthreads();
    }
    if (t == 0)
        out_loss[0] = (float)(1.25 * (red[0] / (double)((size_t)N * D)));
}

// ---------------------------------------------------------------------------
extern "C" void kernel_launch(void* const* d_in, const int* in_sizes, int n_in,
                              void* d_out, int out_size, void* d_ws, size_t ws_size,
                              hipStream_t stream)
{
    const float* z_e   = (const float*)d_in[0];
    const float* cbook = (const float*)d_in[1];
    const float* csz   = (const float*)d_in[2];
    const float* ema_w = (const float*)d_in[3];

    float* out = (float*)d_out;
    u32*   ws  = (u32*)d_ws;

    float*  cnorm     = (float*)(ws + OFF_CNORM);
    int*    idx_i     = (int*)(ws + OFF_IDX);
    int*    cnti      = (int*)(ws + OFF_CNTI);
    int*    nxt       = (int*)(ws + OFF_NEXT);
    int*    offs      = (int*)(ws + OFF_OFFS);
    int*    list      = (int*)(ws + OFF_LIST);
    double* n_sum     = (double*)(ws + OFF_SUMS);
    int*    flag_cnt  = (int*)(ws + OFF_FLAGC);
    int*    flag_list = (int*)(ws + OFF_FLAGL);
    double* loss_part = (double*)(ws + OFF_LOSSP);

    // bf16-split fragment-order scratch in d_out regions overwritten later:
    u16* X2  = (u16*)(out + OUT_ZQ);    // overwritten by zq_loss
    u16* CB2 = (u16*)(out + OUT_NCB);   // overwritten by finalize

    hipMemsetAsync(ws + OFF_CNTI, 0, (OFF_FLAGC + 1 - OFF_CNTI) * sizeof(u32), stream);

    split_frag_kernel<<<N / 16, 256, 0, stream>>>(z_e, (u32x4*)X2);
    split_frag_kernel<<<K / 16, 256, 0, stream>>>(cbook, (u32x4*)CB2);
    row_norm_kernel<<<K / 4, 256, 0, stream>>>(cbook, cnorm);

    argmin_mfma_kernel<<<N / BP, 512, 0, stream>>>(CB2, X2, cnorm, idx_i,
                                                   out + OUT_IDX, flag_cnt, flag_list);

    exact_kernel<<<256, 256, 0, stream>>>(z_e, cbook, cnorm, flag_cnt, flag_list,
                                          idx_i, out + OUT_IDX);

    zq_loss_kernel<<<N / 2, 256, 0, stream>>>(z_e, cbook, idx_i, out + OUT_ZQ,
                                              cnti, loss_part);

    scan_kernel<<<1, 256, 0, stream>>>(cnti, csz, offs, nxt, out + OUT_NCS, n_sum);

    fill_kernel<<<N / 256, 256, 0, stream>>>(idx_i, nxt, list);

    gather_finalize_kernel<<<K, 128, 0, stream>>>(z_e, offs, list, ema_w,
                                                  out + OUT_NCS, n_sum,
                                                  out + OUT_EMA, out + OUT_NCB);

    loss_reduce_kernel<<<1, 256, 0, stream>>>(loss_part, out + OUT_LOSS);
}

// Round 9
// 1372.075 us; speedup vs baseline: 1.1587x; 1.1587x over previous
//
#include <hip/hip_runtime.h>

// VQ-VAE EMA vector quantizer, MI355X.
// R9: two-level argmin. Pass1 = hi-only bf16 MFMA (1/4 the MFMA issue of the
// split scheme; TAU1=1.0 ~ 10 sigma flags any point whose true best could
// differ). Pass2 = proven R6 split argmin on repacked flagged points,
// K-parallel (64 slot-blocks x 4 code-quadrants) + combine. gap<TAU2 -> exact
// f32. zq/loss fused into gather_finalize. Scatter path otherwise as R7/R8.

constexpr int N = 32768;   // B*L
constexpr int D = 512;
constexpr int K = 8192;
constexpr int CAP = 8192;  // max flagged points through pass2

constexpr float DECAYF  = 0.99f;
constexpr float OMDECAY = (float)(1.0 - 0.99);
constexpr float EPSF    = 1e-6f;
constexpr float KEPSF   = (float)(8192 * 1e-6);
constexpr float TAU1    = 1.0f;    // pass1 hi-only gap threshold (~10 sigma)
constexpr float TAU2    = 0.02f;   // pass2 split-precision gap threshold

typedef unsigned int   u32;
typedef unsigned short u16;
typedef float  f32x4 __attribute__((ext_vector_type(4)));
typedef u32    u32x4 __attribute__((ext_vector_type(4)));
typedef __bf16 bf16x8 __attribute__((ext_vector_type(8)));

#define AS1 __attribute__((address_space(1)))
#define AS3 __attribute__((address_space(3)))

// ---- workspace layout (32-bit word offsets) ----
constexpr size_t OFF_CNORM  = 0;                         // K f32
constexpr size_t OFF_IDX    = OFF_CNORM + K;             // N int
constexpr size_t OFF_CNTI   = OFF_IDX + N;               // K int
constexpr size_t OFF_FLAGC  = OFF_CNTI + K;              // 1 int
constexpr size_t OFF_FLAG2C = OFF_FLAGC + 1;             // 1 int
constexpr size_t OFF_NEXT   = OFF_FLAG2C + 1;            // K int
constexpr size_t OFF_OFFS   = OFF_NEXT + K;              // K+1 int
constexpr size_t OFF_LIST   = OFF_OFFS + K + 1;          // N int
constexpr size_t OFF_FLAGL  = OFF_LIST + N;              // CAP int
constexpr size_t OFF_FLAG2L = OFF_FLAGL + CAP;           // N int
constexpr size_t OFF_PB1    = OFF_FLAG2L + N;            // 4*CAP f32
constexpr size_t OFF_PB2    = OFF_PB1 + 4 * CAP;         // 4*CAP f32
constexpr size_t OFF_PI1    = OFF_PB2 + 4 * CAP;         // 4*CAP int
constexpr size_t OFF_SUMS   = (OFF_PI1 + 4 * CAP + 1) & ~(size_t)1;  // 1 double
constexpr size_t OFF_LOSSP  = (OFF_SUMS + 2 + 1) & ~(size_t)1;       // K doubles
constexpr size_t OFF_CBH    = (OFF_LOSSP + 2 * K + 3) & ~(size_t)3;  // K*512 u16 = K*256 words
constexpr size_t WS_WORDS   = OFF_CBH + (size_t)K * 256;             // ~9.3 MB (ws >= 17MB proven R2)
static_assert((OFF_SUMS & 1) == 0 && (OFF_LOSSP & 1) == 0, "f64 align");
static_assert((OFF_CBH & 3) == 0, "16B align for global_load_lds");

// ---- output layout (float offsets), reference return order ----
constexpr size_t OUT_ZQ   = 0;                          // N*D
constexpr size_t OUT_IDX  = OUT_ZQ + (size_t)N * D;     // N
constexpr size_t OUT_LOSS = OUT_IDX + N;                // 1
constexpr size_t OUT_NCB  = OUT_LOSS + 1;               // K*D
constexpr size_t OUT_NCS  = OUT_NCB + (size_t)K * D;    // K
constexpr size_t OUT_EMA  = OUT_NCS + K;                // K*D
// scratch-in-output: XH at zq+0 (N*512 u16 = 8.39M floats), PX2 at zq+8.39M f
// (CAP*1024 u16), both consumed before gather_finalize writes zq.
constexpr size_t XH_F   = OUT_ZQ;
constexpr size_t PX2_F  = OUT_ZQ + (size_t)N * 256;     // N*512 u16 = N*256 f32
// CB2 interleaved fills OUT_NCB exactly (K*1024 u16 = K*512 f32).

// ---------------------------------------------------------------------------
__device__ inline u16 f32_to_bf16_rne(float f)
{
    u32 u = __builtin_bit_cast(u32, f);
    u = (u + 0x7FFFu + ((u >> 16) & 1u)) >> 16;
    return (u16)u;
}

// hi-only split: [rows/16 tiles][16 slices][64 lanes][8 u16], elem
// ((T*16+S)*64+l)*8+j = bf16_hi(M[T*16+(l&15)][d = S*32 + (l>>4)*8 + j]).
__global__ __launch_bounds__(256) void split_hi_kernel(const float* __restrict__ src,
                                                       u32x4* __restrict__ dst)
{
    const int T = blockIdx.x;
    const int w = threadIdx.x >> 6;
    const int l = threadIdx.x & 63;
    const int row = T * 16 + (l & 15);
#pragma unroll
    for (int i = 0; i < 4; ++i) {
        const int S  = w * 4 + i;
        const int q4 = S * 8 + (l >> 4) * 2;          // float4 index of d0
        const float4 va = ((const float4*)src)[(size_t)row * 128 + q4];
        const float4 vb = ((const float4*)src)[(size_t)row * 128 + q4 + 1];
        const float a[8] = {va.x, va.y, va.z, va.w, vb.x, vb.y, vb.z, vb.w};
        u32x4 o;
#pragma unroll
        for (int j = 0; j < 4; ++j)
            ((u32*)&o)[j] = (u32)f32_to_bf16_rne(a[2 * j]) |
                            ((u32)f32_to_bf16_rne(a[2 * j + 1]) << 16);
        dst[((size_t)T * 16 + S) * 64 + l] = o;
    }
}

// interleaved (hi,lo) split, frag order (R8's proven kernel):
// elem ((R*32+S)*64+l)*8+j2 = M[R*16+(l&15)][k2=S*32+(l>>4)*8+j2], k2=2d->hi.
__global__ __launch_bounds__(256) void split_int_kernel(const float* __restrict__ src,
                                                        u32x4* __restrict__ dst)
{
    const int R = blockIdx.x;
    const int w = threadIdx.x >> 6;
    const int l = threadIdx.x & 63;
    const int row = R * 16 + (l & 15);
    const int cq  = l >> 4;
#pragma unroll
    for (int i = 0; i < 8; ++i) {
        const int S = w + 4 * i;
        const float4 v = ((const float4*)src)[(size_t)row * 128 + S * 4 + cq];
        u32x4 o;
        const float a[4] = {v.x, v.y, v.z, v.w};
#pragma unroll
        for (int j = 0; j < 4; ++j) {
            const u16 hi = f32_to_bf16_rne(a[j]);
            const float hif = __builtin_bit_cast(float, (u32)hi << 16);
            const u16 lo = f32_to_bf16_rne(a[j] - hif);
            ((u32*)&o)[j] = (u32)hi | ((u32)lo << 16);
        }
        dst[((size_t)R * 32 + S) * 64 + l] = o;
    }
}

// indirect split: gather flagged points' rows -> PX2 interleaved frag order.
__global__ __launch_bounds__(256) void repack_kernel(
    const float* __restrict__ z_e, const int* __restrict__ flag_cnt,
    const int* __restrict__ flag_list, u32x4* __restrict__ PX2)
{
    const int B = blockIdx.x;
    const int cnt = min(*flag_cnt, CAP);
    if (B * 16 >= cnt) return;
    const int w = threadIdx.x >> 6;
    const int l = threadIdx.x & 63;
    const int srow = B * 16 + (l & 15);
    const int n = (srow < cnt) ? (flag_list[srow] & (N - 1)) : 0;
    const int cq = l >> 4;
#pragma unroll
    for (int i = 0; i < 8; ++i) {
        const int S = w + 4 * i;
        const float4 v = ((const float4*)z_e)[(size_t)n * 128 + S * 4 + cq];
        u32x4 o;
        const float a[4] = {v.x, v.y, v.z, v.w};
#pragma unroll
        for (int j = 0; j < 4; ++j) {
            const u16 hi = f32_to_bf16_rne(a[j]);
            const float hif = __builtin_bit_cast(float, (u32)hi << 16);
            const u16 lo = f32_to_bf16_rne(a[j] - hif);
            ((u32*)&o)[j] = (u32)hi | ((u32)lo << 16);
        }
        PX2[((size_t)B * 32 + S) * 64 + l] = o;
    }
}

// ---------------------------------------------------------------------------
__global__ __launch_bounds__(256) void row_norm_kernel(const float* __restrict__ a,
                                                       float* __restrict__ out)
{
    const int row  = blockIdx.x * 4 + (threadIdx.x >> 6);
    const int lane = threadIdx.x & 63;
    const float4* r = (const float4*)(a + (size_t)row * D);
    const float4 v0 = r[lane];
    const float4 v1 = r[lane + 64];
    float s = v0.x * v0.x + v0.y * v0.y + v0.z * v0.z + v0.w * v0.w
            + v1.x * v1.x + v1.y * v1.y + v1.z * v1.z + v1.w * v1.w;
#pragma unroll
    for (int m = 32; m >= 1; m >>= 1) s += __shfl_xor(s, m, 64);
    if (lane == 0) out[row] = s;
}

// ---------------------------------------------------------------------------
// Pass 1: hi-only argmin. 512 thr, 128 points/block, 512-code chunks, K=512.
constexpr int BPH = 128, BCH = 512;
constexpr int NSTEPH = 16, NCHUNKH = K / BCH;   // 16 slices/chunk, 16 chunks
constexpr int CELH = BCH * 32;                  // 16384 u16 (32KB)
constexpr int XELH = BPH * 32;                  // 4096 u16 (8KB)
constexpr int BUFH = CELH + XELH;               // 40KB

__global__ __launch_bounds__(512, 2) void argmin_hi_kernel(
    const u16* __restrict__ CBH, const u16* __restrict__ XH,
    const float* __restrict__ cnorm,
    int* __restrict__ idx_i, float* __restrict__ idx_f,
    int* __restrict__ flag_cnt, int* __restrict__ flag_list,
    int* __restrict__ flag2_cnt, int* __restrict__ flag2_list)
{
    __shared__ __align__(16) u16 lds[2][BUFH];   // 80 KB

    const int tid  = threadIdx.x;
    const int w    = tid >> 6;
    const int lane = tid & 63;
    const int lhi  = lane >> 4;
    const int n0   = blockIdx.x * BPH;

    auto stage = [&](u16* bufp, int chunk, int s) {
#pragma unroll
        for (int j = 0; j < 4; ++j) {
            const int slot = j * 512 + tid;
            const u16* gsrc = CBH + (((size_t)(chunk * 32 + (slot >> 6)) * 16 + s) * 64
                                     + (slot & 63)) * 8;
            __builtin_amdgcn_global_load_lds((const AS1 u32*)gsrc,
                                             (AS3 u32*)(bufp + slot * 8), 16, 0, 0);
        }
        const u16* gx = XH + (((size_t)(n0 / 16 + (tid >> 6)) * 16 + s) * 64
                              + (tid & 63)) * 8;
        __builtin_amdgcn_global_load_lds((const AS1 u32*)gx,
                                         (AS3 u32*)(bufp + CELH + tid * 8), 16, 0, 0);
    };

    float b1[8], b2[8]; int i1[8];
#pragma unroll
    for (int p = 0; p < 8; ++p) { b1[p] = INFINITY; b2[p] = INFINITY; i1[p] = 0; }

    for (int chunk = 0; chunk < NCHUNKH; ++chunk) {
        f32x4 acc[4][8];
        const f32x4 zero = {0.f, 0.f, 0.f, 0.f};
#pragma unroll
        for (int cg = 0; cg < 4; ++cg)
#pragma unroll
            for (int p = 0; p < 8; ++p) acc[cg][p] = zero;

        stage(&lds[0][0], chunk, 0);
        __syncthreads();

#pragma unroll 2
        for (int s = 0; s < NSTEPH; ++s) {
            const u16* cur = (s & 1) ? &lds[1][0] : &lds[0][0];
            u16* nxt       = (s & 1) ? &lds[0][0] : &lds[1][0];
            if (s + 1 < NSTEPH) stage(nxt, chunk, s + 1);

            u32x4 bfr[8];
#pragma unroll
            for (int p = 0; p < 8; ++p)
                bfr[p] = *(const u32x4*)(cur + CELH + p * 512 + lane * 8);
#pragma unroll
            for (int cg = 0; cg < 4; ++cg) {
                const u32x4 af = *(const u32x4*)(cur + (w * 4 + cg) * 512 + lane * 8);
#pragma unroll
                for (int p = 0; p < 8; ++p)
                    acc[cg][p] = __builtin_amdgcn_mfma_f32_16x16x32_bf16(
                        __builtin_bit_cast(bf16x8, af), __builtin_bit_cast(bf16x8, bfr[p]),
                        acc[cg][p], 0, 0, 0);
            }
            __syncthreads();
        }

        const int cb0 = chunk * BCH + w * 64;
#pragma unroll
        for (int cg = 0; cg < 4; ++cg) {
            const int code0 = cb0 + cg * 16 + lhi * 4;
            const float4 cn4 = *(const float4*)(cnorm + code0);
            const float cn[4] = {cn4.x, cn4.y, cn4.z, cn4.w};
#pragma unroll
            for (int p = 0; p < 8; ++p) {
                const f32x4 A = acc[cg][p];
                const float dv[4] = {cn[0] - 2.f * A.x, cn[1] - 2.f * A.y,
                                     cn[2] - 2.f * A.z, cn[3] - 2.f * A.w};
#pragma unroll
                for (int r = 0; r < 4; ++r) {
                    if (dv[r] < b1[p]) { b2[p] = b1[p]; b1[p] = dv[r]; i1[p] = code0 + r; }
                    else if (dv[r] < b2[p]) { b2[p] = dv[r]; }
                }
            }
        }
    }

#pragma unroll
    for (int p = 0; p < 8; ++p) {
#pragma unroll
        for (int m = 16; m <= 32; m <<= 1) {
            const float ob1 = __shfl_xor(b1[p], m, 64);
            const float ob2 = __shfl_xor(b2[p], m, 64);
            const int   oi1 = __shfl_xor(i1[p], m, 64);
            const float nb2 = fminf(fminf(b2[p], ob2), fmaxf(b1[p], ob1));
            if (ob1 < b1[p] || (ob1 == b1[p] && oi1 < i1[p])) { b1[p] = ob1; i1[p] = oi1; }
            b2[p] = nb2;
        }
    }

    __syncthreads();

    float* mb1 = (float*)&lds[0][0];
    float* mb2 = mb1 + 8 * BPH;
    int*   mi  = (int*)(mb2 + 8 * BPH);
    if (lane < 16) {
#pragma unroll
        for (int p = 0; p < 8; ++p) {
            const int pt = p * 16 + lane;
            mb1[w * BPH + pt] = b1[p];
            mb2[w * BPH + pt] = b2[p];
            mi [w * BPH + pt] = i1[p];
        }
    }
    __syncthreads();
    if (tid < BPH) {
        float fb1 = INFINITY, fb2 = INFINITY; int fi = 0;
        for (int ww = 0; ww < 8; ++ww) {
            const float a1 = mb1[ww * BPH + tid], a2 = mb2[ww * BPH + tid];
            const int   ai = mi[ww * BPH + tid];
            const float nb2 = fminf(fminf(fb2, a2), fmaxf(fb1, a1));
            if (a1 < fb1 || (a1 == fb1 && ai < fi)) { fb1 = a1; fi = ai; }
            fb2 = nb2;
        }
        const int n = n0 + tid;
        idx_i[n] = fi;
        idx_f[n] = (float)fi;
        if (fb2 - fb1 < TAU1) {
            const int pos = atomicAdd(flag_cnt, 1);
            if (pos < CAP) flag_list[pos] = n;
            else {                              // overflow -> exact path (correct always)
                const int p2 = atomicAdd(flag2_cnt, 1);
                if ((unsigned)p2 < (unsigned)N) flag2_list[p2] = n;
            }
        }
    }
}

// ---------------------------------------------------------------------------
// Pass 2: split-precision argmin on repacked flagged slots, K-parallel.
// grid 256: q = blockIdx&3 (code quadrant, 2048 codes), sb = blockIdx>>2.
constexpr int CEL2 = 512 * 32;                 // 16384 u16 per step (codes)
constexpr int XEL2 = 128 * 32;
constexpr int BUF2 = CEL2 + XEL2;

__global__ __launch_bounds__(512, 2) void argmin_part_kernel(
    const u16* __restrict__ CB2, const u16* __restrict__ PX2,
    const float* __restrict__ cnorm, const int* __restrict__ flag_cnt,
    float* __restrict__ pb1, float* __restrict__ pb2, int* __restrict__ pi1)
{
    const int q  = blockIdx.x & 3;
    const int sb = blockIdx.x >> 2;
    const int cnt = min(*flag_cnt, CAP);
    if (sb * 128 >= cnt) return;
    const int n0s = sb * 128;

    __shared__ __align__(16) u16 lds[2][BUF2];

    const int tid  = threadIdx.x;
    const int w    = tid >> 6;
    const int lane = tid & 63;
    const int lhi  = lane >> 4;

    auto stage = [&](u16* bufp, int chunk, int s) {
#pragma unroll
        for (int j = 0; j < 4; ++j) {
            const int slot = j * 512 + tid;
            const u16* gsrc = CB2 + (((size_t)(chunk * 32 + (slot >> 6)) * 32 + s) * 512
                                     + (slot & 63) * 8);
            __builtin_amdgcn_global_load_lds((const AS1 u32*)gsrc,
                                             (AS3 u32*)(bufp + slot * 8), 16, 0, 0);
        }
        const u16* gx = PX2 + (((size_t)(n0s / 16 + (tid >> 6)) * 32 + s) * 512
                               + (tid & 63) * 8);
        __builtin_amdgcn_global_load_lds((const AS1 u32*)gx,
                                         (AS3 u32*)(bufp + CEL2 + tid * 8), 16, 0, 0);
    };

    float b1[8], b2[8]; int i1[8];
#pragma unroll
    for (int p = 0; p < 8; ++p) { b1[p] = INFINITY; b2[p] = INFINITY; i1[p] = 0; }

    for (int cc = 0; cc < 4; ++cc) {
        const int chunk = q * 4 + cc;
        f32x4 acc[4][8];
        const f32x4 zero = {0.f, 0.f, 0.f, 0.f};
#pragma unroll
        for (int cg = 0; cg < 4; ++cg)
#pragma unroll
            for (int p = 0; p < 8; ++p) acc[cg][p] = zero;

        stage(&lds[0][0], chunk, 0);
        __syncthreads();

#pragma unroll 2
        for (int s = 0; s < 32; ++s) {
            const u16* cur = (s & 1) ? &lds[1][0] : &lds[0][0];
            u16* nxt       = (s & 1) ? &lds[0][0] : &lds[1][0];
            if (s + 1 < 32) stage(nxt, chunk, s + 1);

            u32x4 bfr[8];
#pragma unroll
            for (int p = 0; p < 8; ++p)
                bfr[p] = *(const u32x4*)(cur + CEL2 + p * 512 + lane * 8);
#pragma unroll
            for (int cg = 0; cg < 4; ++cg) {
                const u32x4 af = *(const u32x4*)(cur + (w * 4 + cg) * 512 + lane * 8);
                u32x4 as;
                as.x = (af.x >> 16) | (af.x << 16);
                as.y = (af.y >> 16) | (af.y << 16);
                as.z = (af.z >> 16) | (af.z << 16);
                as.w = (af.w >> 16) | (af.w << 16);
#pragma unroll
                for (int p = 0; p < 8; ++p) {
                    acc[cg][p] = __builtin_amdgcn_mfma_f32_16x16x32_bf16(
                        __builtin_bit_cast(bf16x8, af), __builtin_bit_cast(bf16x8, bfr[p]),
                        acc[cg][p], 0, 0, 0);
                    acc[cg][p] = __builtin_amdgcn_mfma_f32_16x16x32_bf16(
                        __builtin_bit_cast(bf16x8, as), __builtin_bit_cast(bf16x8, bfr[p]),
                        acc[cg][p], 0, 0, 0);
                }
            }
            __syncthreads();
        }

        const int cb0 = chunk * 512 + w * 64;
#pragma unroll
        for (int cg = 0; cg < 4; ++cg) {
            const int code0 = cb0 + cg * 16 + lhi * 4;
            const float4 cn4 = *(const float4*)(cnorm + code0);
            const float cn[4] = {cn4.x, cn4.y, cn4.z, cn4.w};
#pragma unroll
            for (int p = 0; p < 8; ++p) {
                const f32x4 A = acc[cg][p];
                const float dv[4] = {cn[0] - 2.f * A.x, cn[1] - 2.f * A.y,
                                     cn[2] - 2.f * A.z, cn[3] - 2.f * A.w};
#pragma unroll
                for (int r = 0; r < 4; ++r) {
                    if (dv[r] < b1[p]) { b2[p] = b1[p]; b1[p] = dv[r]; i1[p] = code0 + r; }
                    else if (dv[r] < b2[p]) { b2[p] = dv[r]; }
                }
            }
        }
    }

#pragma unroll
    for (int p = 0; p < 8; ++p) {
#pragma unroll
        for (int m = 16; m <= 32; m <<= 1) {
            const float ob1 = __shfl_xor(b1[p], m, 64);
            const float ob2 = __shfl_xor(b2[p], m, 64);
            const int   oi1 = __shfl_xor(i1[p], m, 64);
            const float nb2 = fminf(fminf(b2[p], ob2), fmaxf(b1[p], ob1));
            if (ob1 < b1[p] || (ob1 == b1[p] && oi1 < i1[p])) { b1[p] = ob1; i1[p] = oi1; }
            b2[p] = nb2;
        }
    }

    __syncthreads();

    float* mb1 = (float*)&lds[0][0];
    float* mb2 = mb1 + 8 * 128;
    int*   mi  = (int*)(mb2 + 8 * 128);
    if (lane < 16) {
#pragma unroll
        for (int p = 0; p < 8; ++p) {
            const int pt = p * 16 + lane;
            mb1[w * 128 + pt] = b1[p];
            mb2[w * 128 + pt] = b2[p];
            mi [w * 128 + pt] = i1[p];
        }
    }
    __syncthreads();
    if (tid < 128) {
        float fb1 = INFINITY, fb2 = INFINITY; int fi = 0;
        for (int ww = 0; ww < 8; ++ww) {
            const float a1 = mb1[ww * 128 + tid], a2 = mb2[ww * 128 + tid];
            const int   ai = mi[ww * 128 + tid];
            const float nb2 = fminf(fminf(fb2, a2), fmaxf(fb1, a1));
            if (a1 < fb1 || (a1 == fb1 && ai < fi)) { fb1 = a1; fi = ai; }
            fb2 = nb2;
        }
        const int slot = n0s + tid;
        pb1[q * CAP + slot] = fb1;
        pb2[q * CAP + slot] = fb2;
        pi1[q * CAP + slot] = fi;
    }
}

// ---------------------------------------------------------------------------
// merge the 4 code-quadrant partials per flagged slot.
__global__ __launch_bounds__(256) void combine_kernel(
    const int* __restrict__ flag_cnt, const int* __restrict__ flag_list,
    const float* __restrict__ pb1, const float* __restrict__ pb2,
    const int* __restrict__ pi1,
    int* __restrict__ idx_i, float* __restrict__ idx_f,
    int* __restrict__ flag2_cnt, int* __restrict__ flag2_list)
{
    const int s = blockIdx.x * 256 + threadIdx.x;
    const int cnt = min(*flag_cnt, CAP);
    if (s >= cnt) return;
    float fb1 = INFINITY, fb2 = INFINITY; int fi = 0x7fffffff;
#pragma unroll
    for (int q = 0; q < 4; ++q) {
        const float a1 = pb1[q * CAP + s], a2 = pb2[q * CAP + s];
        const int   ai = pi1[q * CAP + s];
        const float nb2 = fminf(fminf(fb2, a2), fmaxf(fb1, a1));
        if (a1 < fb1 || (a1 == fb1 && ai < fi)) { fb1 = a1; fi = ai; }
        fb2 = nb2;
    }
    const int n = flag_list[s] & (N - 1);
    idx_i[n] = fi;
    idx_f[n] = (float)fi;
    if (fb2 - fb1 < TAU2) {
        const int p2 = atomicAdd(flag2_cnt, 1);
        if ((unsigned)p2 < (unsigned)N) flag2_list[p2] = n;
    }
}

// ---------------------------------------------------------------------------
// exact f32 re-scan (flag2). Wave-per-quarter, coalesced.
__global__ __launch_bounds__(256) void exact_kernel(
    const float* __restrict__ x, const float* __restrict__ cb,
    const float* __restrict__ cnorm, const int* __restrict__ flag_cnt,
    const int* __restrict__ flag_list, int* __restrict__ idx_i, float* __restrict__ idx_f)
{
    __shared__ float xs[D];
    __shared__ float wbv[4];
    __shared__ int   wbi[4];
    const int cnt  = min(*flag_cnt, N);
    const int wv   = threadIdx.x >> 6;
    const int lane = threadIdx.x & 63;
    for (int i = blockIdx.x; i < cnt; i += gridDim.x) {
        const int n = flag_list[i] & (N - 1);
        __syncthreads();
        if (threadIdx.x < 128)
            ((float4*)xs)[threadIdx.x] = ((const float4*)(x + (size_t)n * D))[threadIdx.x];
        __syncthreads();
        const float4 xa = ((const float4*)xs)[lane * 2];
        const float4 xb = ((const float4*)xs)[lane * 2 + 1];
        float best = INFINITY; int besti = K;
        for (int k = wv * (K / 4); k < (wv + 1) * (K / 4); ++k) {
            const float4* c4 = (const float4*)(cb + (size_t)k * D) + lane * 2;
            const float4 ca = c4[0], cb4 = c4[1];
            float s = xa.x * ca.x + xa.y * ca.y + xa.z * ca.z + xa.w * ca.w
                    + xb.x * cb4.x + xb.y * cb4.y + xb.z * cb4.z + xb.w * cb4.w;
#pragma unroll
            for (int m = 32; m >= 1; m >>= 1) s += __shfl_xor(s, m, 64);
            const float dist = cnorm[k] - 2.0f * s;
            if (dist < best) { best = dist; besti = k; }
        }
        if (lane == 0) { wbv[wv] = best; wbi[wv] = besti; }
        __syncthreads();
        if (threadIdx.x == 0) {
            float fb = wbv[0]; int fi = wbi[0];
            for (int j = 1; j < 4; ++j)
                if (wbv[j] < fb) { fb = wbv[j]; fi = wbi[j]; }
            idx_i[n] = fi;
            idx_f[n] = (float)fi;
        }
        __syncthreads();
    }
}

// ---------------------------------------------------------------------------
__global__ __launch_bounds__(256) void count_kernel(
    const int* __restrict__ idx_i, int* __restrict__ cnti)
{
    const int p = blockIdx.x * 256 + threadIdx.x;
    atomicAdd(&cnti[idx_i[p] & (K - 1)], 1);
}

// ---------------------------------------------------------------------------
__global__ __launch_bounds__(256) void scan_kernel(
    const int* __restrict__ cnti, const float* __restrict__ csz,
    int* __restrict__ offs, int* __restrict__ nxt,
    float* __restrict__ ncs, double* __restrict__ n_sum)
{
    __shared__ int    tsum[256];
    __shared__ double dsum[256];
    const int t = threadIdx.x;
    const int base = t * 32;
    int s = 0;
    double dn = 0.0;
#pragma unroll
    for (int i = 0; i < 32; ++i) {
        const int c = cnti[base + i];
        s += c;
        const float v = DECAYF * csz[base + i] + OMDECAY * (float)c;
        ncs[base + i] = v;
        dn += (double)v;
    }
    tsum[t] = s; dsum[t] = dn;
    __syncthreads();
    int run = 0;
    for (int j = 0; j < t; ++j) run += tsum[j];
#pragma unroll
    for (int i = 0; i < 32; ++i) {
        offs[base + i] = run;
        nxt[base + i] = run;
        run += cnti[base + i];
    }
    if (t == 255) offs[K] = run;
    if (t == 0) {
        double tot = 0.0;
        for (int j = 0; j < 256; ++j) tot += dsum[j];
        n_sum[0] = tot;
    }
}

// ---------------------------------------------------------------------------
__global__ __launch_bounds__(256) void fill_kernel(
    const int* __restrict__ idx_i, int* __restrict__ nxt, int* __restrict__ list)
{
    const int p = blockIdx.x * 256 + threadIdx.x;
    const int k = idx_i[p] & (K - 1);
    const int pos = atomicAdd(&nxt[k], 1);
    if ((unsigned)pos < (unsigned)N) list[pos] = p;
}

// ---------------------------------------------------------------------------
// block per code: dw gather + EMA + finalize + zq write + loss partial.
__global__ __launch_bounds__(128) void gather_finalize_kernel(
    const float* __restrict__ x, const float* __restrict__ cb,
    const int* __restrict__ offs, const int* __restrict__ list,
    const float* __restrict__ ema_w, const float* __restrict__ ncs,
    const double* __restrict__ n_sum, float* __restrict__ new_ema,
    float* __restrict__ new_cb, float* __restrict__ zq,
    double* __restrict__ loss_part)
{
    const int k = blockIdx.x;
    const int t = threadIdx.x;
    const int beg = min(offs[k], N), end = min(offs[k + 1], N);
    const size_t o = (size_t)k * 128 + t;
    const float4 c = ((const float4*)cb)[o];
    float4 acc = {0.f, 0.f, 0.f, 0.f};
    float lsum = 0.f;
    for (int i = beg; i < end; ++i) {
        const int p = list[i] & (N - 1);
        const float4 v = ((const float4*)x)[(size_t)p * 128 + t];
        acc.x += v.x; acc.y += v.y; acc.z += v.z; acc.w += v.w;
        ((float4*)zq)[(size_t)p * 128 + t] = c;
        const float d0 = v.x - c.x, d1 = v.y - c.y, d2 = v.z - c.z, d3 = v.w - c.w;
        lsum += d0 * d0 + d1 * d1 + d2 * d2 + d3 * d3;
    }
    const float n = (float)n_sum[0];
    const float csm = (ncs[k] + EPSF) / (n + KEPSF) * n;
    const float4 e = ((const float4*)ema_w)[o];
    float4 ne;
    ne.x = DECAYF * e.x + OMDECAY * acc.x;
    ne.y = DECAYF * e.y + OMDECAY * acc.y;
    ne.z = DECAYF * e.z + OMDECAY * acc.z;
    ne.w = DECAYF * e.w + OMDECAY * acc.w;
    ((float4*)new_ema)[o] = ne;
    float4 nc;
    nc.x = ne.x / csm; nc.y = ne.y / csm; nc.z = ne.z / csm; nc.w = ne.w / csm;
    ((float4*)new_cb)[o] = nc;

#pragma unroll
    for (int m = 32; m >= 1; m >>= 1) lsum += __shfl_xor(lsum, m, 64);
    __shared__ float prt[2];
    if ((t & 63) == 0) prt[t >> 6] = lsum;
    __syncthreads();
    if (t == 0) loss_part[k] = (double)(prt[0] + prt[1]);
}

// ---------------------------------------------------------------------------
__global__ __launch_bounds__(256) void loss_reduce_kernel(
    const double* __restrict__ loss_part, float* __restrict__ out_loss)
{
    __shared__ double red[256];
    const int t = threadIdx.x;
    double s = 0.0;
    for (int i = t; i < K; i += 256) s += loss_part[i];
    red[t] = s;
    __syncthreads();
    for (int off = 128; off > 0; off >>= 1) {
        if (t < off) red[t] += red[t + off];
        __syncthreads();
    }
    if (t == 0)
        out_loss[0] = (float)(1.25 * (red[0] / (double)((size_t)N * D)));
}

// ---------------------------------------------------------------------------
extern "C" void kernel_launch(void* const* d_in, const int* in_sizes, int n_in,
                              void* d_out, int out_size, void* d_ws, size_t ws_size,
                              hipStream_t stream)
{
    const float* z_e   = (const float*)d_in[0];
    const float* cbook = (const float*)d_in[1];
    const float* csz   = (const float*)d_in[2];
    const float* ema_w = (const float*)d_in[3];

    float* out = (float*)d_out;
    u32*   ws  = (u32*)d_ws;

    float*  cnorm      = (float*)(ws + OFF_CNORM);
    int*    idx_i      = (int*)(ws + OFF_IDX);
    int*    cnti       = (int*)(ws + OFF_CNTI);
    int*    flag_cnt   = (int*)(ws + OFF_FLAGC);
    int*    flag2_cnt  = (int*)(ws + OFF_FLAG2C);
    int*    nxt        = (int*)(ws + OFF_NEXT);
    int*    offs       = (int*)(ws + OFF_OFFS);
    int*    list       = (int*)(ws + OFF_LIST);
    int*    flag_list  = (int*)(ws + OFF_FLAGL);
    int*    flag2_list = (int*)(ws + OFF_FLAG2L);
    float*  pb1        = (float*)(ws + OFF_PB1);
    float*  pb2        = (float*)(ws + OFF_PB2);
    int*    pi1        = (int*)(ws + OFF_PI1);
    double* n_sum      = (double*)(ws + OFF_SUMS);
    double* loss_part  = (double*)(ws + OFF_LOSSP);
    u16*    CBH        = (u16*)(ws + OFF_CBH);

    u16* XH  = (u16*)(out + XH_F);     // consumed before zq written
    u16* PX2 = (u16*)(out + PX2_F);    // consumed before zq written
    u16* CB2 = (u16*)(out + OUT_NCB);  // consumed before new_cb written

    // zero: cnti (K) + flag_cnt + flag2_cnt (contiguous)
    hipMemsetAsync(ws + OFF_CNTI, 0, (K + 2) * sizeof(u32), stream);

    split_hi_kernel<<<N / 16, 256, 0, stream>>>(z_e, (u32x4*)XH);
    split_hi_kernel<<<K / 16, 256, 0, stream>>>(cbook, (u32x4*)CBH);
    split_int_kernel<<<K / 16, 256, 0, stream>>>(cbook, (u32x4*)CB2);
    row_norm_kernel<<<K / 4, 256, 0, stream>>>(cbook, cnorm);

    argmin_hi_kernel<<<N / BPH, 512, 0, stream>>>(CBH, XH, cnorm, idx_i,
                                                  out + OUT_IDX, flag_cnt, flag_list,
                                                  flag2_cnt, flag2_list);

    repack_kernel<<<CAP / 16, 256, 0, stream>>>(z_e, flag_cnt, flag_list, (u32x4*)PX2);

    argmin_part_kernel<<<(CAP / 128) * 4, 512, 0, stream>>>(CB2, PX2, cnorm, flag_cnt,
                                                            pb1, pb2, pi1);

    combine_kernel<<<CAP / 256, 256, 0, stream>>>(flag_cnt, flag_list, pb1, pb2, pi1,
                                                  idx_i, out + OUT_IDX,
                                                  flag2_cnt, flag2_list);

    exact_kernel<<<256, 256, 0, stream>>>(z_e, cbook, cnorm, flag2_cnt, flag2_list,
                                          idx_i, out + OUT_IDX);

    count_kernel<<<N / 256, 256, 0, stream>>>(idx_i, cnti);

    scan_kernel<<<1, 256, 0, stream>>>(cnti, csz, offs, nxt, out + OUT_NCS, n_sum);

    fill_kernel<<<N / 256, 256, 0, stream>>>(idx_i, nxt, list);

    gather_finalize_kernel<<<K, 128, 0, stream>>>(z_e, cbook, offs, list, ema_w,
                                                  out + OUT_NCS, n_sum,
                                                  out + OUT_EMA, out + OUT_NCB,
                                                  out + OUT_ZQ, loss_part);

    loss_reduce_kernel<<<1, 256, 0, stream>>>(loss_part, out + OUT_LOSS);
}

// Round 10
// 864.205 us; speedup vs baseline: 1.8396x; 1.5877x over previous
//
#include <hip/hip_runtime.h>

// VQ-VAE EMA vector quantizer, MI355X.
// R10: (1) exact rescan parallelized — (point, 512-code chunk) blocks, thread-
// per-code f32 dots, block-reduce, one u64 atomicMin per block (R9's wave-serial
// exact was 525us latency-bound at 2% occupancy); (2) argmin_part split 16-way
// over K (one 512-code chunk per block); (3) rest identical to R9.

constexpr int N = 32768;   // B*L
constexpr int D = 512;
constexpr int K = 8192;
constexpr int CAP  = 8192; // max flagged points through pass2
constexpr int CAPE = 4096; // max points through exact pass

constexpr float DECAYF  = 0.99f;
constexpr float OMDECAY = (float)(1.0 - 0.99);
constexpr float EPSF    = 1e-6f;
constexpr float KEPSF   = (float)(8192 * 1e-6);
constexpr float TAU1    = 1.0f;    // pass1 hi-only gap threshold (~8 sigma)
constexpr float TAU2    = 0.02f;   // pass2 split-precision gap threshold

typedef unsigned int       u32;
typedef unsigned short     u16;
typedef unsigned long long u64;
typedef float  f32x4 __attribute__((ext_vector_type(4)));
typedef u32    u32x4 __attribute__((ext_vector_type(4)));
typedef __bf16 bf16x8 __attribute__((ext_vector_type(8)));

#define AS1 __attribute__((address_space(1)))
#define AS3 __attribute__((address_space(3)))

// ---- workspace layout (32-bit word offsets) ----
constexpr size_t OFF_CNORM  = 0;                          // K f32
constexpr size_t OFF_IDX    = OFF_CNORM + K;              // N int
constexpr size_t OFF_CNTI   = OFF_IDX + N;                // K int
constexpr size_t OFF_FLAGC  = OFF_CNTI + K;               // 1 int
constexpr size_t OFF_FLAG2C = OFF_FLAGC + 1;              // 1 int
constexpr size_t OFF_NEXT   = OFF_FLAG2C + 1;             // K int
constexpr size_t OFF_OFFS   = OFF_NEXT + K;               // K+1 int
constexpr size_t OFF_LIST   = OFF_OFFS + K + 1;           // N int
constexpr size_t OFF_FLAGL  = OFF_LIST + N;               // CAP int
constexpr size_t OFF_FLAG2L = OFF_FLAGL + CAP;            // N int
constexpr size_t OFF_PB1    = OFF_FLAG2L + N;             // 16*CAP f32
constexpr size_t OFF_PB2    = OFF_PB1 + 16 * CAP;         // 16*CAP f32
constexpr size_t OFF_PI1    = OFF_PB2 + 16 * CAP;         // 16*CAP int
constexpr size_t OFF_ESLOT  = (OFF_PI1 + 16 * CAP + 1) & ~(size_t)1;  // CAPE u64
constexpr size_t OFF_SUMS   = (OFF_ESLOT + 2 * CAPE + 1) & ~(size_t)1; // 1 double
constexpr size_t OFF_LOSSP  = (OFF_SUMS + 2 + 1) & ~(size_t)1;         // K doubles
constexpr size_t OFF_CBH    = (OFF_LOSSP + 2 * K + 3) & ~(size_t)3;    // K*256 words
static_assert((OFF_ESLOT & 1) == 0 && (OFF_SUMS & 1) == 0 && (OFF_LOSSP & 1) == 0, "align");
static_assert((OFF_CBH & 3) == 0, "16B align for global_load_lds");

// ---- output layout (float offsets), reference return order ----
constexpr size_t OUT_ZQ   = 0;                          // N*D
constexpr size_t OUT_IDX  = OUT_ZQ + (size_t)N * D;     // N
constexpr size_t OUT_LOSS = OUT_IDX + N;                // 1
constexpr size_t OUT_NCB  = OUT_LOSS + 1;               // K*D
constexpr size_t OUT_NCS  = OUT_NCB + (size_t)K * D;    // K
constexpr size_t OUT_EMA  = OUT_NCS + K;                // K*D
// scratch-in-output (consumed before the owning kernel writes the region):
constexpr size_t XH_F  = OUT_ZQ;                        // N*512 u16
constexpr size_t PX2_F = OUT_ZQ + (size_t)N * 256;      // CAP*1024 u16

// ---------------------------------------------------------------------------
__device__ inline u16 f32_to_bf16_rne(float f)
{
    u32 u = __builtin_bit_cast(u32, f);
    u = (u + 0x7FFFu + ((u >> 16) & 1u)) >> 16;
    return (u16)u;
}

// hi-only split: [rows/16][16 slices][64 lanes][8 u16]
__global__ __launch_bounds__(256) void split_hi_kernel(const float* __restrict__ src,
                                                       u32x4* __restrict__ dst)
{
    const int T = blockIdx.x;
    const int w = threadIdx.x >> 6;
    const int l = threadIdx.x & 63;
    const int row = T * 16 + (l & 15);
#pragma unroll
    for (int i = 0; i < 4; ++i) {
        const int S  = w * 4 + i;
        const int q4 = S * 8 + (l >> 4) * 2;
        const float4 va = ((const float4*)src)[(size_t)row * 128 + q4];
        const float4 vb = ((const float4*)src)[(size_t)row * 128 + q4 + 1];
        const float a[8] = {va.x, va.y, va.z, va.w, vb.x, vb.y, vb.z, vb.w};
        u32x4 o;
#pragma unroll
        for (int j = 0; j < 4; ++j)
            ((u32*)&o)[j] = (u32)f32_to_bf16_rne(a[2 * j]) |
                            ((u32)f32_to_bf16_rne(a[2 * j + 1]) << 16);
        dst[((size_t)T * 16 + S) * 64 + l] = o;
    }
}

// interleaved (hi,lo) split, frag order
__global__ __launch_bounds__(256) void split_int_kernel(const float* __restrict__ src,
                                                        u32x4* __restrict__ dst)
{
    const int R = blockIdx.x;
    const int w = threadIdx.x >> 6;
    const int l = threadIdx.x & 63;
    const int row = R * 16 + (l & 15);
    const int cq  = l >> 4;
#pragma unroll
    for (int i = 0; i < 8; ++i) {
        const int S = w + 4 * i;
        const float4 v = ((const float4*)src)[(size_t)row * 128 + S * 4 + cq];
        u32x4 o;
        const float a[4] = {v.x, v.y, v.z, v.w};
#pragma unroll
        for (int j = 0; j < 4; ++j) {
            const u16 hi = f32_to_bf16_rne(a[j]);
            const float hif = __builtin_bit_cast(float, (u32)hi << 16);
            const u16 lo = f32_to_bf16_rne(a[j] - hif);
            ((u32*)&o)[j] = (u32)hi | ((u32)lo << 16);
        }
        dst[((size_t)R * 32 + S) * 64 + l] = o;
    }
}

// indirect split of flagged points -> PX2 interleaved frag order
__global__ __launch_bounds__(256) void repack_kernel(
    const float* __restrict__ z_e, const int* __restrict__ flag_cnt,
    const int* __restrict__ flag_list, u32x4* __restrict__ PX2)
{
    const int B = blockIdx.x;
    const int cnt = min(*flag_cnt, CAP);
    if (B * 16 >= cnt) return;
    const int w = threadIdx.x >> 6;
    const int l = threadIdx.x & 63;
    const int srow = B * 16 + (l & 15);
    const int n = (srow < cnt) ? (flag_list[srow] & (N - 1)) : 0;
    const int cq = l >> 4;
#pragma unroll
    for (int i = 0; i < 8; ++i) {
        const int S = w + 4 * i;
        const float4 v = ((const float4*)z_e)[(size_t)n * 128 + S * 4 + cq];
        u32x4 o;
        const float a[4] = {v.x, v.y, v.z, v.w};
#pragma unroll
        for (int j = 0; j < 4; ++j) {
            const u16 hi = f32_to_bf16_rne(a[j]);
            const float hif = __builtin_bit_cast(float, (u32)hi << 16);
            const u16 lo = f32_to_bf16_rne(a[j] - hif);
            ((u32*)&o)[j] = (u32)hi | ((u32)lo << 16);
        }
        PX2[((size_t)B * 32 + S) * 64 + l] = o;
    }
}

// ---------------------------------------------------------------------------
__global__ __launch_bounds__(256) void row_norm_kernel(const float* __restrict__ a,
                                                       float* __restrict__ out)
{
    const int row  = blockIdx.x * 4 + (threadIdx.x >> 6);
    const int lane = threadIdx.x & 63;
    const float4* r = (const float4*)(a + (size_t)row * D);
    const float4 v0 = r[lane];
    const float4 v1 = r[lane + 64];
    float s = v0.x * v0.x + v0.y * v0.y + v0.z * v0.z + v0.w * v0.w
            + v1.x * v1.x + v1.y * v1.y + v1.z * v1.z + v1.w * v1.w;
#pragma unroll
    for (int m = 32; m >= 1; m >>= 1) s += __shfl_xor(s, m, 64);
    if (lane == 0) out[row] = s;
}

// ---------------------------------------------------------------------------
// Pass 1: hi-only argmin. 512 thr, 128 points/block, 512-code chunks.
constexpr int BPH = 128, BCH = 512;
constexpr int NSTEPH = 16, NCHUNKH = K / BCH;
constexpr int CELH = BCH * 32;
constexpr int XELH = BPH * 32;
constexpr int BUFH = CELH + XELH;

__global__ __launch_bounds__(512, 2) void argmin_hi_kernel(
    const u16* __restrict__ CBH, const u16* __restrict__ XH,
    const float* __restrict__ cnorm,
    int* __restrict__ idx_i, float* __restrict__ idx_f,
    int* __restrict__ flag_cnt, int* __restrict__ flag_list,
    int* __restrict__ flag2_cnt, int* __restrict__ flag2_list)
{
    __shared__ __align__(16) u16 lds[2][BUFH];

    const int tid  = threadIdx.x;
    const int w    = tid >> 6;
    const int lane = tid & 63;
    const int lhi  = lane >> 4;
    const int n0   = blockIdx.x * BPH;

    auto stage = [&](u16* bufp, int chunk, int s) {
#pragma unroll
        for (int j = 0; j < 4; ++j) {
            const int slot = j * 512 + tid;
            const u16* gsrc = CBH + (((size_t)(chunk * 32 + (slot >> 6)) * 16 + s) * 64
                                     + (slot & 63)) * 8;
            __builtin_amdgcn_global_load_lds((const AS1 u32*)gsrc,
                                             (AS3 u32*)(bufp + slot * 8), 16, 0, 0);
        }
        const u16* gx = XH + (((size_t)(n0 / 16 + (tid >> 6)) * 16 + s) * 64
                              + (tid & 63)) * 8;
        __builtin_amdgcn_global_load_lds((const AS1 u32*)gx,
                                         (AS3 u32*)(bufp + CELH + tid * 8), 16, 0, 0);
    };

    float b1[8], b2[8]; int i1[8];
#pragma unroll
    for (int p = 0; p < 8; ++p) { b1[p] = INFINITY; b2[p] = INFINITY; i1[p] = 0; }

    for (int chunk = 0; chunk < NCHUNKH; ++chunk) {
        f32x4 acc[4][8];
        const f32x4 zero = {0.f, 0.f, 0.f, 0.f};
#pragma unroll
        for (int cg = 0; cg < 4; ++cg)
#pragma unroll
            for (int p = 0; p < 8; ++p) acc[cg][p] = zero;

        stage(&lds[0][0], chunk, 0);
        __syncthreads();

#pragma unroll 2
        for (int s = 0; s < NSTEPH; ++s) {
            const u16* cur = (s & 1) ? &lds[1][0] : &lds[0][0];
            u16* nxt       = (s & 1) ? &lds[0][0] : &lds[1][0];
            if (s + 1 < NSTEPH) stage(nxt, chunk, s + 1);

            u32x4 bfr[8];
#pragma unroll
            for (int p = 0; p < 8; ++p)
                bfr[p] = *(const u32x4*)(cur + CELH + p * 512 + lane * 8);
#pragma unroll
            for (int cg = 0; cg < 4; ++cg) {
                const u32x4 af = *(const u32x4*)(cur + (w * 4 + cg) * 512 + lane * 8);
#pragma unroll
                for (int p = 0; p < 8; ++p)
                    acc[cg][p] = __builtin_amdgcn_mfma_f32_16x16x32_bf16(
                        __builtin_bit_cast(bf16x8, af), __builtin_bit_cast(bf16x8, bfr[p]),
                        acc[cg][p], 0, 0, 0);
            }
            __syncthreads();
        }

        const int cb0 = chunk * BCH + w * 64;
#pragma unroll
        for (int cg = 0; cg < 4; ++cg) {
            const int code0 = cb0 + cg * 16 + lhi * 4;
            const float4 cn4 = *(const float4*)(cnorm + code0);
            const float cn[4] = {cn4.x, cn4.y, cn4.z, cn4.w};
#pragma unroll
            for (int p = 0; p < 8; ++p) {
                const f32x4 A = acc[cg][p];
                const float dv[4] = {cn[0] - 2.f * A.x, cn[1] - 2.f * A.y,
                                     cn[2] - 2.f * A.z, cn[3] - 2.f * A.w};
#pragma unroll
                for (int r = 0; r < 4; ++r) {
                    if (dv[r] < b1[p]) { b2[p] = b1[p]; b1[p] = dv[r]; i1[p] = code0 + r; }
                    else if (dv[r] < b2[p]) { b2[p] = dv[r]; }
                }
            }
        }
    }

#pragma unroll
    for (int p = 0; p < 8; ++p) {
#pragma unroll
        for (int m = 16; m <= 32; m <<= 1) {
            const float ob1 = __shfl_xor(b1[p], m, 64);
            const float ob2 = __shfl_xor(b2[p], m, 64);
            const int   oi1 = __shfl_xor(i1[p], m, 64);
            const float nb2 = fminf(fminf(b2[p], ob2), fmaxf(b1[p], ob1));
            if (ob1 < b1[p] || (ob1 == b1[p] && oi1 < i1[p])) { b1[p] = ob1; i1[p] = oi1; }
            b2[p] = nb2;
        }
    }

    __syncthreads();

    float* mb1 = (float*)&lds[0][0];
    float* mb2 = mb1 + 8 * BPH;
    int*   mi  = (int*)(mb2 + 8 * BPH);
    if (lane < 16) {
#pragma unroll
        for (int p = 0; p < 8; ++p) {
            const int pt = p * 16 + lane;
            mb1[w * BPH + pt] = b1[p];
            mb2[w * BPH + pt] = b2[p];
            mi [w * BPH + pt] = i1[p];
        }
    }
    __syncthreads();
    if (tid < BPH) {
        float fb1 = INFINITY, fb2 = INFINITY; int fi = 0;
        for (int ww = 0; ww < 8; ++ww) {
            const float a1 = mb1[ww * BPH + tid], a2 = mb2[ww * BPH + tid];
            const int   ai = mi[ww * BPH + tid];
            const float nb2 = fminf(fminf(fb2, a2), fmaxf(fb1, a1));
            if (a1 < fb1 || (a1 == fb1 && ai < fi)) { fb1 = a1; fi = ai; }
            fb2 = nb2;
        }
        const int n = n0 + tid;
        idx_i[n] = fi;
        idx_f[n] = (float)fi;
        if (fb2 - fb1 < TAU1) {
            const int pos = atomicAdd(flag_cnt, 1);
            if (pos < CAP) flag_list[pos] = n;
            else {
                const int p2 = atomicAdd(flag2_cnt, 1);
                if ((unsigned)p2 < (unsigned)N) flag2_list[p2] = n;
            }
        }
    }
}

// ---------------------------------------------------------------------------
// Pass 2: split-precision argmin, ONE 512-code chunk per block.
// grid (CAP/128)*16: sb = blockIdx>>4 (slot block), q = blockIdx&15 (chunk).
constexpr int CEL2 = 512 * 32;
constexpr int XEL2 = 128 * 32;
constexpr int BUF2 = CEL2 + XEL2;

__global__ __launch_bounds__(512, 2) void argmin_part_kernel(
    const u16* __restrict__ CB2, const u16* __restrict__ PX2,
    const float* __restrict__ cnorm, const int* __restrict__ flag_cnt,
    float* __restrict__ pb1, float* __restrict__ pb2, int* __restrict__ pi1)
{
    const int q  = blockIdx.x & 15;
    const int sb = blockIdx.x >> 4;
    const int cnt = min(*flag_cnt, CAP);
    if (sb * 128 >= cnt) return;
    const int n0s = sb * 128;

    __shared__ __align__(16) u16 lds[2][BUF2];

    const int tid  = threadIdx.x;
    const int w    = tid >> 6;
    const int lane = tid & 63;
    const int lhi  = lane >> 4;

    auto stage = [&](u16* bufp, int s) {
#pragma unroll
        for (int j = 0; j < 4; ++j) {
            const int slot = j * 512 + tid;
            const u16* gsrc = CB2 + (((size_t)(q * 32 + (slot >> 6)) * 32 + s) * 512
                                     + (slot & 63) * 8);
            __builtin_amdgcn_global_load_lds((const AS1 u32*)gsrc,
                                             (AS3 u32*)(bufp + slot * 8), 16, 0, 0);
        }
        const u16* gx = PX2 + (((size_t)(n0s / 16 + (tid >> 6)) * 32 + s) * 512
                               + (tid & 63) * 8);
        __builtin_amdgcn_global_load_lds((const AS1 u32*)gx,
                                         (AS3 u32*)(bufp + CEL2 + tid * 8), 16, 0, 0);
    };

    float b1[8], b2[8]; int i1[8];
#pragma unroll
    for (int p = 0; p < 8; ++p) { b1[p] = INFINITY; b2[p] = INFINITY; i1[p] = 0; }

    f32x4 acc[4][8];
    const f32x4 zero = {0.f, 0.f, 0.f, 0.f};
#pragma unroll
    for (int cg = 0; cg < 4; ++cg)
#pragma unroll
        for (int p = 0; p < 8; ++p) acc[cg][p] = zero;

    stage(&lds[0][0], 0);
    __syncthreads();

#pragma unroll 2
    for (int s = 0; s < 32; ++s) {
        const u16* cur = (s & 1) ? &lds[1][0] : &lds[0][0];
        u16* nxt       = (s & 1) ? &lds[0][0] : &lds[1][0];
        if (s + 1 < 32) stage(nxt, s + 1);

        u32x4 bfr[8];
#pragma unroll
        for (int p = 0; p < 8; ++p)
            bfr[p] = *(const u32x4*)(cur + CEL2 + p * 512 + lane * 8);
#pragma unroll
        for (int cg = 0; cg < 4; ++cg) {
            const u32x4 af = *(const u32x4*)(cur + (w * 4 + cg) * 512 + lane * 8);
            u32x4 as;
            as.x = (af.x >> 16) | (af.x << 16);
            as.y = (af.y >> 16) | (af.y << 16);
            as.z = (af.z >> 16) | (af.z << 16);
            as.w = (af.w >> 16) | (af.w << 16);
#pragma unroll
            for (int p = 0; p < 8; ++p) {
                acc[cg][p] = __builtin_amdgcn_mfma_f32_16x16x32_bf16(
                    __builtin_bit_cast(bf16x8, af), __builtin_bit_cast(bf16x8, bfr[p]),
                    acc[cg][p], 0, 0, 0);
                acc[cg][p] = __builtin_amdgcn_mfma_f32_16x16x32_bf16(
                    __builtin_bit_cast(bf16x8, as), __builtin_bit_cast(bf16x8, bfr[p]),
                    acc[cg][p], 0, 0, 0);
            }
        }
        __syncthreads();
    }

    const int cb0 = q * 512 + w * 64;
#pragma unroll
    for (int cg = 0; cg < 4; ++cg) {
        const int code0 = cb0 + cg * 16 + lhi * 4;
        const float4 cn4 = *(const float4*)(cnorm + code0);
        const float cn[4] = {cn4.x, cn4.y, cn4.z, cn4.w};
#pragma unroll
        for (int p = 0; p < 8; ++p) {
            const f32x4 A = acc[cg][p];
            const float dv[4] = {cn[0] - 2.f * A.x, cn[1] - 2.f * A.y,
                                 cn[2] - 2.f * A.z, cn[3] - 2.f * A.w};
#pragma unroll
            for (int r = 0; r < 4; ++r) {
                if (dv[r] < b1[p]) { b2[p] = b1[p]; b1[p] = dv[r]; i1[p] = code0 + r; }
                else if (dv[r] < b2[p]) { b2[p] = dv[r]; }
            }
        }
    }

#pragma unroll
    for (int p = 0; p < 8; ++p) {
#pragma unroll
        for (int m = 16; m <= 32; m <<= 1) {
            const float ob1 = __shfl_xor(b1[p], m, 64);
            const float ob2 = __shfl_xor(b2[p], m, 64);
            const int   oi1 = __shfl_xor(i1[p], m, 64);
            const float nb2 = fminf(fminf(b2[p], ob2), fmaxf(b1[p], ob1));
            if (ob1 < b1[p] || (ob1 == b1[p] && oi1 < i1[p])) { b1[p] = ob1; i1[p] = oi1; }
            b2[p] = nb2;
        }
    }

    __syncthreads();

    float* mb1 = (float*)&lds[0][0];
    float* mb2 = mb1 + 8 * 128;
    int*   mi  = (int*)(mb2 + 8 * 128);
    if (lane < 16) {
#pragma unroll
        for (int p = 0; p < 8; ++p) {
            const int pt = p * 16 + lane;
            mb1[w * 128 + pt] = b1[p];
            mb2[w * 128 + pt] = b2[p];
            mi [w * 128 + pt] = i1[p];
        }
    }
    __syncthreads();
    if (tid < 128) {
        float fb1 = INFINITY, fb2 = INFINITY; int fi = 0;
        for (int ww = 0; ww < 8; ++ww) {
            const float a1 = mb1[ww * 128 + tid], a2 = mb2[ww * 128 + tid];
            const int   ai = mi[ww * 128 + tid];
            const float nb2 = fminf(fminf(fb2, a2), fmaxf(fb1, a1));
            if (a1 < fb1 || (a1 == fb1 && ai < fi)) { fb1 = a1; fi = ai; }
            fb2 = nb2;
        }
        const int slot = n0s + tid;
        pb1[q * CAP + slot] = fb1;
        pb2[q * CAP + slot] = fb2;
        pi1[q * CAP + slot] = fi;
    }
}

// ---------------------------------------------------------------------------
// merge the 16 code-chunk partials per flagged slot.
__global__ __launch_bounds__(256) void combine_kernel(
    const int* __restrict__ flag_cnt, const int* __restrict__ flag_list,
    const float* __restrict__ pb1, const float* __restrict__ pb2,
    const int* __restrict__ pi1,
    int* __restrict__ idx_i, float* __restrict__ idx_f,
    int* __restrict__ flag2_cnt, int* __restrict__ flag2_list)
{
    const int s = blockIdx.x * 256 + threadIdx.x;
    const int cnt = min(*flag_cnt, CAP);
    if (s >= cnt) return;
    float fb1 = INFINITY, fb2 = INFINITY; int fi = 0x7fffffff;
#pragma unroll
    for (int q = 0; q < 16; ++q) {
        const float a1 = pb1[q * CAP + s], a2 = pb2[q * CAP + s];
        const int   ai = pi1[q * CAP + s];
        const float nb2 = fminf(fminf(fb2, a2), fmaxf(fb1, a1));
        if (a1 < fb1 || (a1 == fb1 && ai < fi)) { fb1 = a1; fi = ai; }
        fb2 = nb2;
    }
    const int n = flag_list[s] & (N - 1);
    idx_i[n] = fi;
    idx_f[n] = (float)fi;
    if (fb2 - fb1 < TAU2) {
        const int p2 = atomicAdd(flag2_cnt, 1);
        if ((unsigned)p2 < (unsigned)N) flag2_list[p2] = n;
    }
}

// ---------------------------------------------------------------------------
// exact f32 rescan, parallel: work item = (flag2 slot, 512-code chunk).
// Thread-per-code dots, block u64-reduce, one atomicMin per block.
__global__ __launch_bounds__(256) void exact_part_kernel(
    const float* __restrict__ x, const float* __restrict__ cb,
    const float* __restrict__ cnorm, const int* __restrict__ flag2_cnt,
    const int* __restrict__ flag2_list, u64* __restrict__ eslot)
{
    __shared__ float4 xs[128];
    __shared__ u64 red[256];
    const int cnt = min(*flag2_cnt, CAPE);
    const int nwork = cnt * 16;
    for (int j = blockIdx.x; j < nwork; j += gridDim.x) {
        const int s = j >> 4;
        const int q = j & 15;
        const int n = flag2_list[s] & (N - 1);
        __syncthreads();
        if (threadIdx.x < 128)
            xs[threadIdx.x] = ((const float4*)(x + (size_t)n * D))[threadIdx.x];
        __syncthreads();
        u64 bestp = ~0ull;
#pragma unroll
        for (int c = 0; c < 2; ++c) {
            const int k = q * 512 + c * 256 + threadIdx.x;
            const float4* crow = (const float4*)(cb + (size_t)k * D);
            float a0 = 0.f, a1 = 0.f, a2 = 0.f, a3 = 0.f;
            for (int d = 0; d < 128; ++d) {
                const float4 xv = xs[d], cv = crow[d];
                a0 = fmaf(xv.x, cv.x, a0);
                a1 = fmaf(xv.y, cv.y, a1);
                a2 = fmaf(xv.z, cv.z, a2);
                a3 = fmaf(xv.w, cv.w, a3);
            }
            const float dist = cnorm[k] - 2.0f * ((a0 + a1) + (a2 + a3));
            u32 ub = __builtin_bit_cast(u32, dist);
            ub = (ub & 0x80000000u) ? ~ub : (ub | 0x80000000u);  // order-preserving
            const u64 pk = ((u64)ub << 32) | (u32)k;
            bestp = bestp < pk ? bestp : pk;
        }
        red[threadIdx.x] = bestp;
        __syncthreads();
        for (int off = 128; off > 0; off >>= 1) {
            if (threadIdx.x < off) {
                const u64 o = red[threadIdx.x + off];
                if (o < red[threadIdx.x]) red[threadIdx.x] = o;
            }
            __syncthreads();
        }
        if (threadIdx.x == 0) atomicMin(&eslot[s], red[0]);
    }
}

__global__ __launch_bounds__(256) void exact_write_kernel(
    const int* __restrict__ flag2_cnt, const int* __restrict__ flag2_list,
    const u64* __restrict__ eslot, int* __restrict__ idx_i, float* __restrict__ idx_f)
{
    const int s = blockIdx.x * 256 + threadIdx.x;
    const int cnt = min(*flag2_cnt, CAPE);
    if (s >= cnt) return;
    const int n = flag2_list[s] & (N - 1);
    const int k = (int)(eslot[s] & (u64)(K - 1));
    idx_i[n] = k;
    idx_f[n] = (float)k;
}

// ---------------------------------------------------------------------------
__global__ __launch_bounds__(256) void count_kernel(
    const int* __restrict__ idx_i, int* __restrict__ cnti)
{
    const int p = blockIdx.x * 256 + threadIdx.x;
    atomicAdd(&cnti[idx_i[p] & (K - 1)], 1);
}

// ---------------------------------------------------------------------------
__global__ __launch_bounds__(256) void scan_kernel(
    const int* __restrict__ cnti, const float* __restrict__ csz,
    int* __restrict__ offs, int* __restrict__ nxt,
    float* __restrict__ ncs, double* __restrict__ n_sum)
{
    __shared__ int    tsum[256];
    __shared__ double dsum[256];
    const int t = threadIdx.x;
    const int base = t * 32;
    int s = 0;
    double dn = 0.0;
#pragma unroll
    for (int i = 0; i < 32; ++i) {
        const int c = cnti[base + i];
        s += c;
        const float v = DECAYF * csz[base + i] + OMDECAY * (float)c;
        ncs[base + i] = v;
        dn += (double)v;
    }
    tsum[t] = s; dsum[t] = dn;
    __syncthreads();
    int run = 0;
    for (int j = 0; j < t; ++j) run += tsum[j];
#pragma unroll
    for (int i = 0; i < 32; ++i) {
        offs[base + i] = run;
        nxt[base + i] = run;
        run += cnti[base + i];
    }
    if (t == 255) offs[K] = run;
    if (t == 0) {
        double tot = 0.0;
        for (int j = 0; j < 256; ++j) tot += dsum[j];
        n_sum[0] = tot;
    }
}

// ---------------------------------------------------------------------------
__global__ __launch_bounds__(256) void fill_kernel(
    const int* __restrict__ idx_i, int* __restrict__ nxt, int* __restrict__ list)
{
    const int p = blockIdx.x * 256 + threadIdx.x;
    const int k = idx_i[p] & (K - 1);
    const int pos = atomicAdd(&nxt[k], 1);
    if ((unsigned)pos < (unsigned)N) list[pos] = p;
}

// ---------------------------------------------------------------------------
__global__ __launch_bounds__(128) void gather_finalize_kernel(
    const float* __restrict__ x, const float* __restrict__ cb,
    const int* __restrict__ offs, const int* __restrict__ list,
    const float* __restrict__ ema_w, const float* __restrict__ ncs,
    const double* __restrict__ n_sum, float* __restrict__ new_ema,
    float* __restrict__ new_cb, float* __restrict__ zq,
    double* __restrict__ loss_part)
{
    const int k = blockIdx.x;
    const int t = threadIdx.x;
    const int beg = min(offs[k], N), end = min(offs[k + 1], N);
    const size_t o = (size_t)k * 128 + t;
    const float4 c = ((const float4*)cb)[o];
    float4 acc = {0.f, 0.f, 0.f, 0.f};
    float lsum = 0.f;
    for (int i = beg; i < end; ++i) {
        const int p = list[i] & (N - 1);
        const float4 v = ((const float4*)x)[(size_t)p * 128 + t];
        acc.x += v.x; acc.y += v.y; acc.z += v.z; acc.w += v.w;
        ((float4*)zq)[(size_t)p * 128 + t] = c;
        const float d0 = v.x - c.x, d1 = v.y - c.y, d2 = v.z - c.z, d3 = v.w - c.w;
        lsum += d0 * d0 + d1 * d1 + d2 * d2 + d3 * d3;
    }
    const float n = (float)n_sum[0];
    const float csm = (ncs[k] + EPSF) / (n + KEPSF) * n;
    const float4 e = ((const float4*)ema_w)[o];
    float4 ne;
    ne.x = DECAYF * e.x + OMDECAY * acc.x;
    ne.y = DECAYF * e.y + OMDECAY * acc.y;
    ne.z = DECAYF * e.z + OMDECAY * acc.z;
    ne.w = DECAYF * e.w + OMDECAY * acc.w;
    ((float4*)new_ema)[o] = ne;
    float4 nc;
    nc.x = ne.x / csm; nc.y = ne.y / csm; nc.z = ne.z / csm; nc.w = ne.w / csm;
    ((float4*)new_cb)[o] = nc;

#pragma unroll
    for (int m = 32; m >= 1; m >>= 1) lsum += __shfl_xor(lsum, m, 64);
    __shared__ float prt[2];
    if ((t & 63) == 0) prt[t >> 6] = lsum;
    __syncthreads();
    if (t == 0) loss_part[k] = (double)(prt[0] + prt[1]);
}

// ---------------------------------------------------------------------------
__global__ __launch_bounds__(256) void loss_reduce_kernel(
    const double* __restrict__ loss_part, float* __restrict__ out_loss)
{
    __shared__ double red[256];
    const int t = threadIdx.x;
    double s = 0.0;
    for (int i = t; i < K; i += 256) s += loss_part[i];
    red[t] = s;
    __syncthreads();
    for (int off = 128; off > 0; off >>= 1) {
        if (t < off) red[t] += red[t + off];
        __syncthreads();
    }
    if (t == 0)
        out_loss[0] = (float)(1.25 * (red[0] / (double)((size_t)N * D)));
}

// ---------------------------------------------------------------------------
extern "C" void kernel_launch(void* const* d_in, const int* in_sizes, int n_in,
                              void* d_out, int out_size, void* d_ws, size_t ws_size,
                              hipStream_t stream)
{
    const float* z_e   = (const float*)d_in[0];
    const float* cbook = (const float*)d_in[1];
    const float* csz   = (const float*)d_in[2];
    const float* ema_w = (const float*)d_in[3];

    float* out = (float*)d_out;
    u32*   ws  = (u32*)d_ws;

    float*  cnorm      = (float*)(ws + OFF_CNORM);
    int*    idx_i      = (int*)(ws + OFF_IDX);
    int*    cnti       = (int*)(ws + OFF_CNTI);
    int*    flag_cnt   = (int*)(ws + OFF_FLAGC);
    int*    flag2_cnt  = (int*)(ws + OFF_FLAG2C);
    int*    nxt        = (int*)(ws + OFF_NEXT);
    int*    offs       = (int*)(ws + OFF_OFFS);
    int*    list       = (int*)(ws + OFF_LIST);
    int*    flag_list  = (int*)(ws + OFF_FLAGL);
    int*    flag2_list = (int*)(ws + OFF_FLAG2L);
    float*  pb1        = (float*)(ws + OFF_PB1);
    float*  pb2        = (float*)(ws + OFF_PB2);
    int*    pi1        = (int*)(ws + OFF_PI1);
    u64*    eslot      = (u64*)(ws + OFF_ESLOT);
    double* n_sum      = (double*)(ws + OFF_SUMS);
    double* loss_part  = (double*)(ws + OFF_LOSSP);
    u16*    CBH        = (u16*)(ws + OFF_CBH);

    u16* XH  = (u16*)(out + XH_F);     // consumed before zq written
    u16* PX2 = (u16*)(out + PX2_F);    // consumed before zq written
    u16* CB2 = (u16*)(out + OUT_NCB);  // consumed before new_cb written

    // zero: cnti (K) + flag_cnt + flag2_cnt; 0xFF: eslot (CAPE u64)
    hipMemsetAsync(ws + OFF_CNTI, 0, (K + 2) * sizeof(u32), stream);
    hipMemsetAsync(ws + OFF_ESLOT, 0xFF, CAPE * sizeof(u64), stream);

    split_hi_kernel<<<N / 16, 256, 0, stream>>>(z_e, (u32x4*)XH);
    split_hi_kernel<<<K / 16, 256, 0, stream>>>(cbook, (u32x4*)CBH);
    split_int_kernel<<<K / 16, 256, 0, stream>>>(cbook, (u32x4*)CB2);
    row_norm_kernel<<<K / 4, 256, 0, stream>>>(cbook, cnorm);

    argmin_hi_kernel<<<N / BPH, 512, 0, stream>>>(CBH, XH, cnorm, idx_i,
                                                  out + OUT_IDX, flag_cnt, flag_list,
                                                  flag2_cnt, flag2_list);

    repack_kernel<<<CAP / 16, 256, 0, stream>>>(z_e, flag_cnt, flag_list, (u32x4*)PX2);

    argmin_part_kernel<<<(CAP / 128) * 16, 512, 0, stream>>>(CB2, PX2, cnorm, flag_cnt,
                                                             pb1, pb2, pi1);

    combine_kernel<<<CAP / 256, 256, 0, stream>>>(flag_cnt, flag_list, pb1, pb2, pi1,
                                                  idx_i, out + OUT_IDX,
                                                  flag2_cnt, flag2_list);

    exact_part_kernel<<<2048, 256, 0, stream>>>(z_e, cbook, cnorm, flag2_cnt,
                                                flag2_list, eslot);

    exact_write_kernel<<<CAPE / 256, 256, 0, stream>>>(flag2_cnt, flag2_list, eslot,
                                                       idx_i, out + OUT_IDX);

    count_kernel<<<N / 256, 256, 0, stream>>>(idx_i, cnti);

    scan_kernel<<<1, 256, 0, stream>>>(cnti, csz, offs, nxt, out + OUT_NCS, n_sum);

    fill_kernel<<<N / 256, 256, 0, stream>>>(idx_i, nxt, list);

    gather_finalize_kernel<<<K, 128, 0, stream>>>(z_e, cbook, offs, list, ema_w,
                                                  out + OUT_NCS, n_sum,
                                                  out + OUT_EMA, out + OUT_NCB,
                                                  out + OUT_ZQ, loss_part);

    loss_reduce_kernel<<<1, 256, 0, stream>>>(loss_part, out + OUT_LOSS);
}

// Round 11
// 841.270 us; speedup vs baseline: 1.8898x; 1.0273x over previous
//
#include <hip/hip_runtime.h>

// VQ-VAE EMA vector quantizer, MI355X.
// R11: argmin_hi restructured — KI=64 (2 k-slices/step, 128 steps instead of
// 256, LDS 2x80KB=160KB) + strength-reduced u32 offset addressing (was 64-bit
// mad chains recomputed per step -> 48% VALUBusy). All other kernels = R10.

constexpr int N = 32768;   // B*L
constexpr int D = 512;
constexpr int K = 8192;
constexpr int CAP  = 8192; // max flagged points through pass2
constexpr int CAPE = 4096; // max points through exact pass

constexpr float DECAYF  = 0.99f;
constexpr float OMDECAY = (float)(1.0 - 0.99);
constexpr float EPSF    = 1e-6f;
constexpr float KEPSF   = (float)(8192 * 1e-6);
constexpr float TAU1    = 1.0f;    // pass1 hi-only gap threshold
constexpr float TAU2    = 0.02f;   // pass2 split-precision gap threshold

typedef unsigned int       u32;
typedef unsigned short     u16;
typedef unsigned long long u64;
typedef float  f32x4 __attribute__((ext_vector_type(4)));
typedef u32    u32x4 __attribute__((ext_vector_type(4)));
typedef __bf16 bf16x8 __attribute__((ext_vector_type(8)));

#define AS1 __attribute__((address_space(1)))
#define AS3 __attribute__((address_space(3)))

// ---- workspace layout (32-bit word offsets) ----
constexpr size_t OFF_CNORM  = 0;                          // K f32
constexpr size_t OFF_IDX    = OFF_CNORM + K;              // N int
constexpr size_t OFF_CNTI   = OFF_IDX + N;                // K int
constexpr size_t OFF_FLAGC  = OFF_CNTI + K;               // 1 int
constexpr size_t OFF_FLAG2C = OFF_FLAGC + 1;              // 1 int
constexpr size_t OFF_NEXT   = OFF_FLAG2C + 1;             // K int
constexpr size_t OFF_OFFS   = OFF_NEXT + K;               // K+1 int
constexpr size_t OFF_LIST   = OFF_OFFS + K + 1;           // N int
constexpr size_t OFF_FLAGL  = OFF_LIST + N;               // CAP int
constexpr size_t OFF_FLAG2L = OFF_FLAGL + CAP;            // N int
constexpr size_t OFF_PB1    = OFF_FLAG2L + N;             // 16*CAP f32
constexpr size_t OFF_PB2    = OFF_PB1 + 16 * CAP;         // 16*CAP f32
constexpr size_t OFF_PI1    = OFF_PB2 + 16 * CAP;         // 16*CAP int
constexpr size_t OFF_ESLOT  = (OFF_PI1 + 16 * CAP + 1) & ~(size_t)1;  // CAPE u64
constexpr size_t OFF_SUMS   = (OFF_ESLOT + 2 * CAPE + 1) & ~(size_t)1; // 1 double
constexpr size_t OFF_LOSSP  = (OFF_SUMS + 2 + 1) & ~(size_t)1;         // K doubles
constexpr size_t OFF_CBH    = (OFF_LOSSP + 2 * K + 3) & ~(size_t)3;    // K*256 words
static_assert((OFF_ESLOT & 1) == 0 && (OFF_SUMS & 1) == 0 && (OFF_LOSSP & 1) == 0, "align");
static_assert((OFF_CBH & 3) == 0, "16B align for global_load_lds");

// ---- output layout (float offsets), reference return order ----
constexpr size_t OUT_ZQ   = 0;                          // N*D
constexpr size_t OUT_IDX  = OUT_ZQ + (size_t)N * D;     // N
constexpr size_t OUT_LOSS = OUT_IDX + N;                // 1
constexpr size_t OUT_NCB  = OUT_LOSS + 1;               // K*D
constexpr size_t OUT_NCS  = OUT_NCB + (size_t)K * D;    // K
constexpr size_t OUT_EMA  = OUT_NCS + K;                // K*D
// scratch-in-output (consumed before the owning kernel writes the region):
constexpr size_t XH_F  = OUT_ZQ;                        // N*512 u16
constexpr size_t PX2_F = OUT_ZQ + (size_t)N * 256;      // CAP*1024 u16

// ---------------------------------------------------------------------------
__device__ inline u16 f32_to_bf16_rne(float f)
{
    u32 u = __builtin_bit_cast(u32, f);
    u = (u + 0x7FFFu + ((u >> 16) & 1u)) >> 16;
    return (u16)u;
}

// hi-only split: [rows/16][16 slices][64 lanes][8 u16]
__global__ __launch_bounds__(256) void split_hi_kernel(const float* __restrict__ src,
                                                       u32x4* __restrict__ dst)
{
    const int T = blockIdx.x;
    const int w = threadIdx.x >> 6;
    const int l = threadIdx.x & 63;
    const int row = T * 16 + (l & 15);
#pragma unroll
    for (int i = 0; i < 4; ++i) {
        const int S  = w * 4 + i;
        const int q4 = S * 8 + (l >> 4) * 2;
        const float4 va = ((const float4*)src)[(size_t)row * 128 + q4];
        const float4 vb = ((const float4*)src)[(size_t)row * 128 + q4 + 1];
        const float a[8] = {va.x, va.y, va.z, va.w, vb.x, vb.y, vb.z, vb.w};
        u32x4 o;
#pragma unroll
        for (int j = 0; j < 4; ++j)
            ((u32*)&o)[j] = (u32)f32_to_bf16_rne(a[2 * j]) |
                            ((u32)f32_to_bf16_rne(a[2 * j + 1]) << 16);
        dst[((size_t)T * 16 + S) * 64 + l] = o;
    }
}

// interleaved (hi,lo) split, frag order
__global__ __launch_bounds__(256) void split_int_kernel(const float* __restrict__ src,
                                                        u32x4* __restrict__ dst)
{
    const int R = blockIdx.x;
    const int w = threadIdx.x >> 6;
    const int l = threadIdx.x & 63;
    const int row = R * 16 + (l & 15);
    const int cq  = l >> 4;
#pragma unroll
    for (int i = 0; i < 8; ++i) {
        const int S = w + 4 * i;
        const float4 v = ((const float4*)src)[(size_t)row * 128 + S * 4 + cq];
        u32x4 o;
        const float a[4] = {v.x, v.y, v.z, v.w};
#pragma unroll
        for (int j = 0; j < 4; ++j) {
            const u16 hi = f32_to_bf16_rne(a[j]);
            const float hif = __builtin_bit_cast(float, (u32)hi << 16);
            const u16 lo = f32_to_bf16_rne(a[j] - hif);
            ((u32*)&o)[j] = (u32)hi | ((u32)lo << 16);
        }
        dst[((size_t)R * 32 + S) * 64 + l] = o;
    }
}

// indirect split of flagged points -> PX2 interleaved frag order
__global__ __launch_bounds__(256) void repack_kernel(
    const float* __restrict__ z_e, const int* __restrict__ flag_cnt,
    const int* __restrict__ flag_list, u32x4* __restrict__ PX2)
{
    const int B = blockIdx.x;
    const int cnt = min(*flag_cnt, CAP);
    if (B * 16 >= cnt) return;
    const int w = threadIdx.x >> 6;
    const int l = threadIdx.x & 63;
    const int srow = B * 16 + (l & 15);
    const int n = (srow < cnt) ? (flag_list[srow] & (N - 1)) : 0;
    const int cq = l >> 4;
#pragma unroll
    for (int i = 0; i < 8; ++i) {
        const int S = w + 4 * i;
        const float4 v = ((const float4*)z_e)[(size_t)n * 128 + S * 4 + cq];
        u32x4 o;
        const float a[4] = {v.x, v.y, v.z, v.w};
#pragma unroll
        for (int j = 0; j < 4; ++j) {
            const u16 hi = f32_to_bf16_rne(a[j]);
            const float hif = __builtin_bit_cast(float, (u32)hi << 16);
            const u16 lo = f32_to_bf16_rne(a[j] - hif);
            ((u32*)&o)[j] = (u32)hi | ((u32)lo << 16);
        }
        PX2[((size_t)B * 32 + S) * 64 + l] = o;
    }
}

// ---------------------------------------------------------------------------
__global__ __launch_bounds__(256) void row_norm_kernel(const float* __restrict__ a,
                                                       float* __restrict__ out)
{
    const int row  = blockIdx.x * 4 + (threadIdx.x >> 6);
    const int lane = threadIdx.x & 63;
    const float4* r = (const float4*)(a + (size_t)row * D);
    const float4 v0 = r[lane];
    const float4 v1 = r[lane + 64];
    float s = v0.x * v0.x + v0.y * v0.y + v0.z * v0.z + v0.w * v0.w
            + v1.x * v1.x + v1.y * v1.y + v1.z * v1.z + v1.w * v1.w;
#pragma unroll
    for (int m = 32; m >= 1; m >>= 1) s += __shfl_xor(s, m, 64);
    if (lane == 0) out[row] = s;
}

// ---------------------------------------------------------------------------
// Pass 1: hi-only argmin. 512 thr, 128 points/block, 512-code chunks,
// KI=64 (2 k-slices/step), 2x80KB LDS, u32 incremental offsets.
constexpr int BPH = 128, BCH = 512, KIH = 64;
constexpr int NSTEPH = 512 / KIH;          // 8 steps/chunk (hi k-range = 512)
constexpr int NCHUNKH = K / BCH;           // 16
constexpr int TOTH = NCHUNKH * NSTEPH;     // 128
constexpr int CELH = BCH * KIH;            // 32768 u16 (64KB)
constexpr int XELH = BPH * KIH;            // 8192 u16 (16KB)
constexpr int BUFH = CELH + XELH;          // 40960 u16 (80KB)

__global__ __launch_bounds__(512, 2) void argmin_hi_kernel(
    const u16* __restrict__ CBH, const u16* __restrict__ XH,
    const float* __restrict__ cnorm,
    int* __restrict__ idx_i, float* __restrict__ idx_f,
    int* __restrict__ flag_cnt, int* __restrict__ flag_list,
    int* __restrict__ flag2_cnt, int* __restrict__ flag2_list)
{
    __shared__ __align__(16) u16 lds[2][BUFH];   // 160 KB

    const int tid  = threadIdx.x;
    const int w    = tid >> 6;
    const int lane = tid & 63;
    const int lhi  = lane >> 4;
    const int n0   = blockIdx.x * BPH;

    // incremental u16-element offsets (slices s,s+1 are contiguous 1024-u16
    // blocks per 16-row group; group stride 8192)
    u32 cbo[8], xo[2];
#pragma unroll
    for (int m = 0; m < 8; ++m) {
        const int flat = m * 512 + tid;                 // [0,4096)
        cbo[m] = (u32)((flat >> 7) * 8192 + (flat & 127) * 8);
    }
#pragma unroll
    for (int m = 0; m < 2; ++m) {
        const int flat = m * 512 + tid;                 // [0,1024)
        xo[m] = (u32)((n0 / 16 + (flat >> 7)) * 8192 + (flat & 127) * 8);
    }

    auto stage = [&](int parity) {
        u16* bufp = &lds[parity][0];
#pragma unroll
        for (int m = 0; m < 8; ++m) {
            __builtin_amdgcn_global_load_lds((const AS1 u32*)(CBH + cbo[m]),
                (AS3 u32*)(bufp + (m * 512 + tid) * 8), 16, 0, 0);
            cbo[m] += 1024;
        }
#pragma unroll
        for (int m = 0; m < 2; ++m) {
            __builtin_amdgcn_global_load_lds((const AS1 u32*)(XH + xo[m]),
                (AS3 u32*)(bufp + CELH + (m * 512 + tid) * 8), 16, 0, 0);
            xo[m] += 1024;
        }
    };

    float b1[8], b2[8]; int i1[8];
#pragma unroll
    for (int p = 0; p < 8; ++p) { b1[p] = INFINITY; b2[p] = INFINITY; i1[p] = 0; }

    stage(0);
    __syncthreads();
    int sc = 1;

    for (int chunk = 0; chunk < NCHUNKH; ++chunk) {
        f32x4 acc[4][8];
        const f32x4 zero = {0.f, 0.f, 0.f, 0.f};
#pragma unroll
        for (int cg = 0; cg < 4; ++cg)
#pragma unroll
            for (int p = 0; p < 8; ++p) acc[cg][p] = zero;

        for (int s8 = 0; s8 < NSTEPH; ++s8) {
            const u16* cur = &lds[s8 & 1][0];
            if (sc < TOTH) {
                if ((sc & (NSTEPH - 1)) == 0) {         // crossing into next chunk
#pragma unroll
                    for (int m = 0; m < 8; ++m) cbo[m] += 262144 - 8192;
#pragma unroll
                    for (int m = 0; m < 2; ++m) xo[m] -= 8192;
                }
                stage(sc & 1);
                ++sc;
            }
#pragma unroll
            for (int sl = 0; sl < 2; ++sl) {
                u32x4 bfr[8];
#pragma unroll
                for (int p = 0; p < 8; ++p)
                    bfr[p] = *(const u32x4*)(cur + CELH + p * 1024 + sl * 512 + lane * 8);
#pragma unroll
                for (int cg = 0; cg < 4; ++cg) {
                    const u32x4 af = *(const u32x4*)(cur + (w * 4 + cg) * 1024
                                                     + sl * 512 + lane * 8);
#pragma unroll
                    for (int p = 0; p < 8; ++p)
                        acc[cg][p] = __builtin_amdgcn_mfma_f32_16x16x32_bf16(
                            __builtin_bit_cast(bf16x8, af),
                            __builtin_bit_cast(bf16x8, bfr[p]), acc[cg][p], 0, 0, 0);
                }
            }
            __syncthreads();
        }

        const int cb0 = chunk * BCH + w * 64;
#pragma unroll
        for (int cg = 0; cg < 4; ++cg) {
            const int code0 = cb0 + cg * 16 + lhi * 4;
            const float4 cn4 = *(const float4*)(cnorm + code0);
            const float cn[4] = {cn4.x, cn4.y, cn4.z, cn4.w};
#pragma unroll
            for (int p = 0; p < 8; ++p) {
                const f32x4 A = acc[cg][p];
                const float dv[4] = {cn[0] - 2.f * A.x, cn[1] - 2.f * A.y,
                                     cn[2] - 2.f * A.z, cn[3] - 2.f * A.w};
#pragma unroll
                for (int r = 0; r < 4; ++r) {
                    if (dv[r] < b1[p]) { b2[p] = b1[p]; b1[p] = dv[r]; i1[p] = code0 + r; }
                    else if (dv[r] < b2[p]) { b2[p] = dv[r]; }
                }
            }
        }
    }

#pragma unroll
    for (int p = 0; p < 8; ++p) {
#pragma unroll
        for (int m = 16; m <= 32; m <<= 1) {
            const float ob1 = __shfl_xor(b1[p], m, 64);
            const float ob2 = __shfl_xor(b2[p], m, 64);
            const int   oi1 = __shfl_xor(i1[p], m, 64);
            const float nb2 = fminf(fminf(b2[p], ob2), fmaxf(b1[p], ob1));
            if (ob1 < b1[p] || (ob1 == b1[p] && oi1 < i1[p])) { b1[p] = ob1; i1[p] = oi1; }
            b2[p] = nb2;
        }
    }

    __syncthreads();

    float* mb1 = (float*)&lds[0][0];
    float* mb2 = mb1 + 8 * BPH;
    int*   mi  = (int*)(mb2 + 8 * BPH);
    if (lane < 16) {
#pragma unroll
        for (int p = 0; p < 8; ++p) {
            const int pt = p * 16 + lane;
            mb1[w * BPH + pt] = b1[p];
            mb2[w * BPH + pt] = b2[p];
            mi [w * BPH + pt] = i1[p];
        }
    }
    __syncthreads();
    if (tid < BPH) {
        float fb1 = INFINITY, fb2 = INFINITY; int fi = 0;
        for (int ww = 0; ww < 8; ++ww) {
            const float a1 = mb1[ww * BPH + tid], a2 = mb2[ww * BPH + tid];
            const int   ai = mi[ww * BPH + tid];
            const float nb2 = fminf(fminf(fb2, a2), fmaxf(fb1, a1));
            if (a1 < fb1 || (a1 == fb1 && ai < fi)) { fb1 = a1; fi = ai; }
            fb2 = nb2;
        }
        const int n = n0 + tid;
        idx_i[n] = fi;
        idx_f[n] = (float)fi;
        if (fb2 - fb1 < TAU1) {
            const int pos = atomicAdd(flag_cnt, 1);
            if (pos < CAP) flag_list[pos] = n;
            else {
                const int p2 = atomicAdd(flag2_cnt, 1);
                if ((unsigned)p2 < (unsigned)N) flag2_list[p2] = n;
            }
        }
    }
}

// ---------------------------------------------------------------------------
// Pass 2: split-precision argmin, ONE 512-code chunk per block.
constexpr int CEL2 = 512 * 32;
constexpr int XEL2 = 128 * 32;
constexpr int BUF2 = CEL2 + XEL2;

__global__ __launch_bounds__(512, 2) void argmin_part_kernel(
    const u16* __restrict__ CB2, const u16* __restrict__ PX2,
    const float* __restrict__ cnorm, const int* __restrict__ flag_cnt,
    float* __restrict__ pb1, float* __restrict__ pb2, int* __restrict__ pi1)
{
    const int q  = blockIdx.x & 15;
    const int sb = blockIdx.x >> 4;
    const int cnt = min(*flag_cnt, CAP);
    if (sb * 128 >= cnt) return;
    const int n0s = sb * 128;

    __shared__ __align__(16) u16 lds[2][BUF2];

    const int tid  = threadIdx.x;
    const int w    = tid >> 6;
    const int lane = tid & 63;
    const int lhi  = lane >> 4;

    auto stage = [&](u16* bufp, int s) {
#pragma unroll
        for (int j = 0; j < 4; ++j) {
            const int slot = j * 512 + tid;
            const u16* gsrc = CB2 + (((size_t)(q * 32 + (slot >> 6)) * 32 + s) * 512
                                     + (slot & 63) * 8);
            __builtin_amdgcn_global_load_lds((const AS1 u32*)gsrc,
                                             (AS3 u32*)(bufp + slot * 8), 16, 0, 0);
        }
        const u16* gx = PX2 + (((size_t)(n0s / 16 + (tid >> 6)) * 32 + s) * 512
                               + (tid & 63) * 8);
        __builtin_amdgcn_global_load_lds((const AS1 u32*)gx,
                                         (AS3 u32*)(bufp + CEL2 + tid * 8), 16, 0, 0);
    };

    float b1[8], b2[8]; int i1[8];
#pragma unroll
    for (int p = 0; p < 8; ++p) { b1[p] = INFINITY; b2[p] = INFINITY; i1[p] = 0; }

    f32x4 acc[4][8];
    const f32x4 zero = {0.f, 0.f, 0.f, 0.f};
#pragma unroll
    for (int cg = 0; cg < 4; ++cg)
#pragma unroll
        for (int p = 0; p < 8; ++p) acc[cg][p] = zero;

    stage(&lds[0][0], 0);
    __syncthreads();

#pragma unroll 2
    for (int s = 0; s < 32; ++s) {
        const u16* cur = (s & 1) ? &lds[1][0] : &lds[0][0];
        u16* nxt       = (s & 1) ? &lds[0][0] : &lds[1][0];
        if (s + 1 < 32) stage(nxt, s + 1);

        u32x4 bfr[8];
#pragma unroll
        for (int p = 0; p < 8; ++p)
            bfr[p] = *(const u32x4*)(cur + CEL2 + p * 512 + lane * 8);
#pragma unroll
        for (int cg = 0; cg < 4; ++cg) {
            const u32x4 af = *(const u32x4*)(cur + (w * 4 + cg) * 512 + lane * 8);
            u32x4 as;
            as.x = (af.x >> 16) | (af.x << 16);
            as.y = (af.y >> 16) | (af.y << 16);
            as.z = (af.z >> 16) | (af.z << 16);
            as.w = (af.w >> 16) | (af.w << 16);
#pragma unroll
            for (int p = 0; p < 8; ++p) {
                acc[cg][p] = __builtin_amdgcn_mfma_f32_16x16x32_bf16(
                    __builtin_bit_cast(bf16x8, af), __builtin_bit_cast(bf16x8, bfr[p]),
                    acc[cg][p], 0, 0, 0);
                acc[cg][p] = __builtin_amdgcn_mfma_f32_16x16x32_bf16(
                    __builtin_bit_cast(bf16x8, as), __builtin_bit_cast(bf16x8, bfr[p]),
                    acc[cg][p], 0, 0, 0);
            }
        }
        __syncthreads();
    }

    const int cb0 = q * 512 + w * 64;
#pragma unroll
    for (int cg = 0; cg < 4; ++cg) {
        const int code0 = cb0 + cg * 16 + lhi * 4;
        const float4 cn4 = *(const float4*)(cnorm + code0);
        const float cn[4] = {cn4.x, cn4.y, cn4.z, cn4.w};
#pragma unroll
        for (int p = 0; p < 8; ++p) {
            const f32x4 A = acc[cg][p];
            const float dv[4] = {cn[0] - 2.f * A.x, cn[1] - 2.f * A.y,
                                 cn[2] - 2.f * A.z, cn[3] - 2.f * A.w};
#pragma unroll
            for (int r = 0; r < 4; ++r) {
                if (dv[r] < b1[p]) { b2[p] = b1[p]; b1[p] = dv[r]; i1[p] = code0 + r; }
                else if (dv[r] < b2[p]) { b2[p] = dv[r]; }
            }
        }
    }

#pragma unroll
    for (int p = 0; p < 8; ++p) {
#pragma unroll
        for (int m = 16; m <= 32; m <<= 1) {
            const float ob1 = __shfl_xor(b1[p], m, 64);
            const float ob2 = __shfl_xor(b2[p], m, 64);
            const int   oi1 = __shfl_xor(i1[p], m, 64);
            const float nb2 = fminf(fminf(b2[p], ob2), fmaxf(b1[p], ob1));
            if (ob1 < b1[p] || (ob1 == b1[p] && oi1 < i1[p])) { b1[p] = ob1; i1[p] = oi1; }
            b2[p] = nb2;
        }
    }

    __syncthreads();

    float* mb1 = (float*)&lds[0][0];
    float* mb2 = mb1 + 8 * 128;
    int*   mi  = (int*)(mb2 + 8 * 128);
    if (lane < 16) {
#pragma unroll
        for (int p = 0; p < 8; ++p) {
            const int pt = p * 16 + lane;
            mb1[w * 128 + pt] = b1[p];
            mb2[w * 128 + pt] = b2[p];
            mi [w * 128 + pt] = i1[p];
        }
    }
    __syncthreads();
    if (tid < 128) {
        float fb1 = INFINITY, fb2 = INFINITY; int fi = 0;
        for (int ww = 0; ww < 8; ++ww) {
            const float a1 = mb1[ww * 128 + tid], a2 = mb2[ww * 128 + tid];
            const int   ai = mi[ww * 128 + tid];
            const float nb2 = fminf(fminf(fb2, a2), fmaxf(fb1, a1));
            if (a1 < fb1 || (a1 == fb1 && ai < fi)) { fb1 = a1; fi = ai; }
            fb2 = nb2;
        }
        const int slot = n0s + tid;
        pb1[q * CAP + slot] = fb1;
        pb2[q * CAP + slot] = fb2;
        pi1[q * CAP + slot] = fi;
    }
}

// ---------------------------------------------------------------------------
__global__ __launch_bounds__(256) void combine_kernel(
    const int* __restrict__ flag_cnt, const int* __restrict__ flag_list,
    const float* __restrict__ pb1, const float* __restrict__ pb2,
    const int* __restrict__ pi1,
    int* __restrict__ idx_i, float* __restrict__ idx_f,
    int* __restrict__ flag2_cnt, int* __restrict__ flag2_list)
{
    const int s = blockIdx.x * 256 + threadIdx.x;
    const int cnt = min(*flag_cnt, CAP);
    if (s >= cnt) return;
    float fb1 = INFINITY, fb2 = INFINITY; int fi = 0x7fffffff;
#pragma unroll
    for (int q = 0; q < 16; ++q) {
        const float a1 = pb1[q * CAP + s], a2 = pb2[q * CAP + s];
        const int   ai = pi1[q * CAP + s];
        const float nb2 = fminf(fminf(fb2, a2), fmaxf(fb1, a1));
        if (a1 < fb1 || (a1 == fb1 && ai < fi)) { fb1 = a1; fi = ai; }
        fb2 = nb2;
    }
    const int n = flag_list[s] & (N - 1);
    idx_i[n] = fi;
    idx_f[n] = (float)fi;
    if (fb2 - fb1 < TAU2) {
        const int p2 = atomicAdd(flag2_cnt, 1);
        if ((unsigned)p2 < (unsigned)N) flag2_list[p2] = n;
    }
}

// ---------------------------------------------------------------------------
__global__ __launch_bounds__(256) void exact_part_kernel(
    const float* __restrict__ x, const float* __restrict__ cb,
    const float* __restrict__ cnorm, const int* __restrict__ flag2_cnt,
    const int* __restrict__ flag2_list, u64* __restrict__ eslot)
{
    __shared__ float4 xs[128];
    __shared__ u64 red[256];
    const int cnt = min(*flag2_cnt, CAPE);
    const int nwork = cnt * 16;
    for (int j = blockIdx.x; j < nwork; j += gridDim.x) {
        const int s = j >> 4;
        const int q = j & 15;
        const int n = flag2_list[s] & (N - 1);
        __syncthreads();
        if (threadIdx.x < 128)
            xs[threadIdx.x] = ((const float4*)(x + (size_t)n * D))[threadIdx.x];
        __syncthreads();
        u64 bestp = ~0ull;
#pragma unroll
        for (int c = 0; c < 2; ++c) {
            const int k = q * 512 + c * 256 + threadIdx.x;
            const float4* crow = (const float4*)(cb + (size_t)k * D);
            float a0 = 0.f, a1 = 0.f, a2 = 0.f, a3 = 0.f;
            for (int d = 0; d < 128; ++d) {
                const float4 xv = xs[d], cv = crow[d];
                a0 = fmaf(xv.x, cv.x, a0);
                a1 = fmaf(xv.y, cv.y, a1);
                a2 = fmaf(xv.z, cv.z, a2);
                a3 = fmaf(xv.w, cv.w, a3);
            }
            const float dist = cnorm[k] - 2.0f * ((a0 + a1) + (a2 + a3));
            u32 ub = __builtin_bit_cast(u32, dist);
            ub = (ub & 0x80000000u) ? ~ub : (ub | 0x80000000u);  // order-preserving
            const u64 pk = ((u64)ub << 32) | (u32)k;
            bestp = bestp < pk ? bestp : pk;
        }
        red[threadIdx.x] = bestp;
        __syncthreads();
        for (int off = 128; off > 0; off >>= 1) {
            if (threadIdx.x < off) {
                const u64 o = red[threadIdx.x + off];
                if (o < red[threadIdx.x]) red[threadIdx.x] = o;
            }
            __syncthreads();
        }
        if (threadIdx.x == 0) atomicMin(&eslot[s], red[0]);
    }
}

__global__ __launch_bounds__(256) void exact_write_kernel(
    const int* __restrict__ flag2_cnt, const int* __restrict__ flag2_list,
    const u64* __restrict__ eslot, int* __restrict__ idx_i, float* __restrict__ idx_f)
{
    const int s = blockIdx.x * 256 + threadIdx.x;
    const int cnt = min(*flag2_cnt, CAPE);
    if (s >= cnt) return;
    const int n = flag2_list[s] & (N - 1);
    const int k = (int)(eslot[s] & (u64)(K - 1));
    idx_i[n] = k;
    idx_f[n] = (float)k;
}

// ---------------------------------------------------------------------------
__global__ __launch_bounds__(256) void count_kernel(
    const int* __restrict__ idx_i, int* __restrict__ cnti)
{
    const int p = blockIdx.x * 256 + threadIdx.x;
    atomicAdd(&cnti[idx_i[p] & (K - 1)], 1);
}

// ---------------------------------------------------------------------------
__global__ __launch_bounds__(256) void scan_kernel(
    const int* __restrict__ cnti, const float* __restrict__ csz,
    int* __restrict__ offs, int* __restrict__ nxt,
    float* __restrict__ ncs, double* __restrict__ n_sum)
{
    __shared__ int    tsum[256];
    __shared__ double dsum[256];
    const int t = threadIdx.x;
    const int base = t * 32;
    int s = 0;
    double dn = 0.0;
#pragma unroll
    for (int i = 0; i < 32; ++i) {
        const int c = cnti[base + i];
        s += c;
        const float v = DECAYF * csz[base + i] + OMDECAY * (float)c;
        ncs[base + i] = v;
        dn += (double)v;
    }
    tsum[t] = s; dsum[t] = dn;
    __syncthreads();
    int run = 0;
    for (int j = 0; j < t; ++j) run += tsum[j];
#pragma unroll
    for (int i = 0; i < 32; ++i) {
        offs[base + i] = run;
        nxt[base + i] = run;
        run += cnti[base + i];
    }
    if (t == 255) offs[K] = run;
    if (t == 0) {
        double tot = 0.0;
        for (int j = 0; j < 256; ++j) tot += dsum[j];
        n_sum[0] = tot;
    }
}

// ---------------------------------------------------------------------------
__global__ __launch_bounds__(256) void fill_kernel(
    const int* __restrict__ idx_i, int* __restrict__ nxt, int* __restrict__ list)
{
    const int p = blockIdx.x * 256 + threadIdx.x;
    const int k = idx_i[p] & (K - 1);
    const int pos = atomicAdd(&nxt[k], 1);
    if ((unsigned)pos < (unsigned)N) list[pos] = p;
}

// ---------------------------------------------------------------------------
__global__ __launch_bounds__(128) void gather_finalize_kernel(
    const float* __restrict__ x, const float* __restrict__ cb,
    const int* __restrict__ offs, const int* __restrict__ list,
    const float* __restrict__ ema_w, const float* __restrict__ ncs,
    const double* __restrict__ n_sum, float* __restrict__ new_ema,
    float* __restrict__ new_cb, float* __restrict__ zq,
    double* __restrict__ loss_part)
{
    const int k = blockIdx.x;
    const int t = threadIdx.x;
    const int beg = min(offs[k], N), end = min(offs[k + 1], N);
    const size_t o = (size_t)k * 128 + t;
    const float4 c = ((const float4*)cb)[o];
    float4 acc = {0.f, 0.f, 0.f, 0.f};
    float lsum = 0.f;
    for (int i = beg; i < end; ++i) {
        const int p = list[i] & (N - 1);
        const float4 v = ((const float4*)x)[(size_t)p * 128 + t];
        acc.x += v.x; acc.y += v.y; acc.z += v.z; acc.w += v.w;
        ((float4*)zq)[(size_t)p * 128 + t] = c;
        const float d0 = v.x - c.x, d1 = v.y - c.y, d2 = v.z - c.z, d3 = v.w - c.w;
        lsum += d0 * d0 + d1 * d1 + d2 * d2 + d3 * d3;
    }
    const float n = (float)n_sum[0];
    const float csm = (ncs[k] + EPSF) / (n + KEPSF) * n;
    const float4 e = ((const float4*)ema_w)[o];
    float4 ne;
    ne.x = DECAYF * e.x + OMDECAY * acc.x;
    ne.y = DECAYF * e.y + OMDECAY * acc.y;
    ne.z = DECAYF * e.z + OMDECAY * acc.z;
    ne.w = DECAYF * e.w + OMDECAY * acc.w;
    ((float4*)new_ema)[o] = ne;
    float4 nc;
    nc.x = ne.x / csm; nc.y = ne.y / csm; nc.z = ne.z / csm; nc.w = ne.w / csm;
    ((float4*)new_cb)[o] = nc;

#pragma unroll
    for (int m = 32; m >= 1; m >>= 1) lsum += __shfl_xor(lsum, m, 64);
    __shared__ float prt[2];
    if ((t & 63) == 0) prt[t >> 6] = lsum;
    __syncthreads();
    if (t == 0) loss_part[k] = (double)(prt[0] + prt[1]);
}

// ---------------------------------------------------------------------------
__global__ __launch_bounds__(256) void loss_reduce_kernel(
    const double* __restrict__ loss_part, float* __restrict__ out_loss)
{
    __shared__ double red[256];
    const int t = threadIdx.x;
    double s = 0.0;
    for (int i = t; i < K; i += 256) s += loss_part[i];
    red[t] = s;
    __syncthreads();
    for (int off = 128; off > 0; off >>= 1) {
        if (t < off) red[t] += red[t + off];
        __syncthreads();
    }
    if (t == 0)
        out_loss[0] = (float)(1.25 * (red[0] / (double)((size_t)N * D)));
}

// ---------------------------------------------------------------------------
extern "C" void kernel_launch(void* const* d_in, const int* in_sizes, int n_in,
                              void* d_out, int out_size, void* d_ws, size_t ws_size,
                              hipStream_t stream)
{
    const float* z_e   = (const float*)d_in[0];
    const float* cbook = (const float*)d_in[1];
    const float* csz   = (const float*)d_in[2];
    const float* ema_w = (const float*)d_in[3];

    float* out = (float*)d_out;
    u32*   ws  = (u32*)d_ws;

    float*  cnorm      = (float*)(ws + OFF_CNORM);
    int*    idx_i      = (int*)(ws + OFF_IDX);
    int*    cnti       = (int*)(ws + OFF_CNTI);
    int*    flag_cnt   = (int*)(ws + OFF_FLAGC);
    int*    flag2_cnt  = (int*)(ws + OFF_FLAG2C);
    int*    nxt        = (int*)(ws + OFF_NEXT);
    int*    offs       = (int*)(ws + OFF_OFFS);
    int*    list       = (int*)(ws + OFF_LIST);
    int*    flag_list  = (int*)(ws + OFF_FLAGL);
    int*    flag2_list = (int*)(ws + OFF_FLAG2L);
    float*  pb1        = (float*)(ws + OFF_PB1);
    float*  pb2        = (float*)(ws + OFF_PB2);
    int*    pi1        = (int*)(ws + OFF_PI1);
    u64*    eslot      = (u64*)(ws + OFF_ESLOT);
    double* n_sum      = (double*)(ws + OFF_SUMS);
    double* loss_part  = (double*)(ws + OFF_LOSSP);
    u16*    CBH        = (u16*)(ws + OFF_CBH);

    u16* XH  = (u16*)(out + XH_F);     // consumed before zq written
    u16* PX2 = (u16*)(out + PX2_F);    // consumed before zq written
    u16* CB2 = (u16*)(out + OUT_NCB);  // consumed before new_cb written

    hipMemsetAsync(ws + OFF_CNTI, 0, (K + 2) * sizeof(u32), stream);
    hipMemsetAsync(ws + OFF_ESLOT, 0xFF, CAPE * sizeof(u64), stream);

    split_hi_kernel<<<N / 16, 256, 0, stream>>>(z_e, (u32x4*)XH);
    split_hi_kernel<<<K / 16, 256, 0, stream>>>(cbook, (u32x4*)CBH);
    split_int_kernel<<<K / 16, 256, 0, stream>>>(cbook, (u32x4*)CB2);
    row_norm_kernel<<<K / 4, 256, 0, stream>>>(cbook, cnorm);

    argmin_hi_kernel<<<N / BPH, 512, 0, stream>>>(CBH, XH, cnorm, idx_i,
                                                  out + OUT_IDX, flag_cnt, flag_list,
                                                  flag2_cnt, flag2_list);

    repack_kernel<<<CAP / 16, 256, 0, stream>>>(z_e, flag_cnt, flag_list, (u32x4*)PX2);

    argmin_part_kernel<<<(CAP / 128) * 16, 512, 0, stream>>>(CB2, PX2, cnorm, flag_cnt,
                                                             pb1, pb2, pi1);

    combine_kernel<<<CAP / 256, 256, 0, stream>>>(flag_cnt, flag_list, pb1, pb2, pi1,
                                                  idx_i, out + OUT_IDX,
                                                  flag2_cnt, flag2_list);

    exact_part_kernel<<<2048, 256, 0, stream>>>(z_e, cbook, cnorm, flag2_cnt,
                                                flag2_list, eslot);

    exact_write_kernel<<<CAPE / 256, 256, 0, stream>>>(flag2_cnt, flag2_list, eslot,
                                                       idx_i, out + OUT_IDX);

    count_kernel<<<N / 256, 256, 0, stream>>>(idx_i, cnti);

    scan_kernel<<<1, 256, 0, stream>>>(cnti, csz, offs, nxt, out + OUT_NCS, n_sum);

    fill_kernel<<<N / 256, 256, 0, stream>>>(idx_i, nxt, list);

    gather_finalize_kernel<<<K, 128, 0, stream>>>(z_e, cbook, offs, list, ema_w,
                                                  out + OUT_NCS, n_sum,
                                                  out + OUT_EMA, out + OUT_NCB,
                                                  out + OUT_ZQ, loss_part);

    loss_reduce_kernel<<<1, 256, 0, stream>>>(loss_part, out + OUT_LOSS);
}